// Round 1
// baseline (737.155 us; speedup 1.0000x reference)
//
#include <hip/hip_runtime.h>
#include <cstdint>
#include <cstddef>

#define DIM_IN 128
#define DIM_HID 64

// ---------- edge dtype detection: int32 (stride 1) vs int64 (stride 2) ----------
// If edge_index is int64 (little-endian, values < 2^31), the odd int32 words of
// the first 64 elements are all zero. For int32 random indices in [0,1e5) the
// probability of that is ~0.
__global__ void k_detect(const int* __restrict__ e, int* __restrict__ flag) {
    if (blockIdx.x == 0 && threadIdx.x == 0) {
        int o = 0;
        for (int j = 1; j < 128; j += 2) o |= e[j];
        flag[0] = (o == 0) ? 2 : 1;
    }
}

// ---------- degree histogram over dst (+1 self-loop added later) ----------
__global__ __launch_bounds__(256) void k_count(const int* __restrict__ eidx,
                                               const int* __restrict__ flag,
                                               int* __restrict__ cnt, int E) {
    int e = blockIdx.x * blockDim.x + threadIdx.x;
    if (e >= E) return;
    int st = flag[0];
    int dst = eidx[(size_t)(E + e) * st];
    atomicAdd(&cnt[dst], 1);
}

// ---------- scan S1: per-1024-chunk sums; also dinv = rsqrt(cnt+1) ----------
__global__ __launch_bounds__(1024) void k_s1(const int* __restrict__ cnt,
                                             float* __restrict__ dinv,
                                             int* __restrict__ bsum, int N) {
    __shared__ int sh[1024];
    int t = threadIdx.x;
    int i = blockIdx.x * 1024 + t;
    int c = (i < N) ? cnt[i] : 0;
    if (i < N) dinv[i] = rsqrtf((float)(c + 1));  // self-loop guarantees deg>=1
    sh[t] = c;
    __syncthreads();
    for (int d = 512; d > 0; d >>= 1) {
        if (t < d) sh[t] += sh[t + d];
        __syncthreads();
    }
    if (t == 0) bsum[blockIdx.x] = sh[0];
}

// ---------- scan S2: exclusive scan of (<=1024) block sums, single thread ----------
__global__ void k_s2(int* __restrict__ bsum, int NB) {
    if (blockIdx.x == 0 && threadIdx.x == 0) {
        int run = 0;
        for (int b = 0; b < NB; b++) { int v = bsum[b]; bsum[b] = run; run += v; }
    }
}

// ---------- scan S3: intra-chunk inclusive scan + base -> offsets & cursor ----------
__global__ __launch_bounds__(1024) void k_s3(const int* __restrict__ cnt,
                                             const int* __restrict__ bsum,
                                             int* __restrict__ offsets,
                                             int* __restrict__ cursor, int N) {
    __shared__ int sh[1024];
    int t = threadIdx.x;
    int i = blockIdx.x * 1024 + t;
    int c = (i < N) ? cnt[i] : 0;
    sh[t] = c;
    __syncthreads();
    for (int d = 1; d < 1024; d <<= 1) {
        int add = (t >= d) ? sh[t - d] : 0;
        __syncthreads();
        sh[t] += add;
        __syncthreads();
    }
    if (i < N) {
        int incl = bsum[blockIdx.x] + sh[t];
        offsets[i + 1] = incl;      // inclusive -> offsets[i+1]
        cursor[i] = incl - c;       // exclusive -> fill cursor
    }
    if (i == 0) offsets[0] = 0;
}

// ---------- CSR fill: csr[pos] = src, bucketed by dst ----------
__global__ __launch_bounds__(256) void k_fill(const int* __restrict__ eidx,
                                              const int* __restrict__ flag,
                                              int* __restrict__ cursor,
                                              int* __restrict__ csr, int E) {
    int e = blockIdx.x * blockDim.x + threadIdx.x;
    if (e >= E) return;
    int st = flag[0];
    int src = eidx[(size_t)e * st];
    int dst = eidx[(size_t)(E + e) * st];
    int pos = atomicAdd(&cursor[dst], 1);
    csr[pos] = src;
}

// ---------- GEMM1: h1 = x @ W1, [N,128]x[128,64] fp32 ----------
// W1 (32KB) staged in LDS; each block does 16 rows, each thread 4 rows x 1 col.
// x-row loads are wave-uniform (rg via readfirstlane) -> scalar-load path.
__global__ __launch_bounds__(256) void k_gemm1(const float* __restrict__ x,
                                               const float* __restrict__ W,
                                               float* __restrict__ h1, int N) {
    __shared__ float Ws[DIM_IN * DIM_HID];
    int t = threadIdx.x;
#pragma unroll
    for (int i = 0; i < 8; i++)
        ((float4*)Ws)[t + 256 * i] = ((const float4*)W)[t + 256 * i];
    __syncthreads();

    int col = t & 63;
    int rg = __builtin_amdgcn_readfirstlane(t >> 6);
    int row0 = blockIdx.x * 16 + rg * 4;
    if (row0 + 3 >= N && row0 >= N) return;  // N divisible by 16 in practice

    const float* xr = x + (size_t)row0 * DIM_IN;
    float a0 = 0.f, a1 = 0.f, a2 = 0.f, a3 = 0.f;
#pragma unroll 4
    for (int k = 0; k < DIM_IN; k++) {
        float w = Ws[k * DIM_HID + col];
        a0 = fmaf(xr[k], w, a0);
        a1 = fmaf(xr[DIM_IN + k], w, a1);
        a2 = fmaf(xr[2 * DIM_IN + k], w, a2);
        a3 = fmaf(xr[3 * DIM_IN + k], w, a3);
    }
    size_t o = (size_t)row0 * DIM_HID + col;
    h1[o] = a0;
    h1[o + DIM_HID] = a1;
    h1[o + 2 * DIM_HID] = a2;
    h1[o + 3 * DIM_HID] = a3;
}

// ---------- agg1 fused: g = relu(A_norm h1 + b1); h2 = g @ W2  ([64,3]) ----------
// One wave per node, lane = feature. Edge loop gathers coalesced 256B h1 rows.
// Epilogue: three 64-lane butterfly reductions give the [1,3] GEMM2 row.
__global__ __launch_bounds__(256) void k_agg1(const float* __restrict__ h1,
                                              const int* __restrict__ csr,
                                              const int* __restrict__ offsets,
                                              const float* __restrict__ dinv,
                                              const float* __restrict__ b1,
                                              const float* __restrict__ W2,
                                              float4* __restrict__ h2, int N) {
    int t = threadIdx.x;
    int lane = t & 63;
    int node = blockIdx.x * 4 + (t >> 6);
    if (node >= N) return;

    float di = dinv[node];
    int beg = offsets[node], end = offsets[node + 1];
    float acc = h1[(size_t)node * 64 + lane] * di * di;  // self-loop

    int e = beg;
    for (; e + 1 < end; e += 2) {
        int s0 = csr[e], s1 = csr[e + 1];
        float w0 = dinv[s0] * di, w1 = dinv[s1] * di;
        acc = fmaf(h1[(size_t)s0 * 64 + lane], w0, acc);
        acc = fmaf(h1[(size_t)s1 * 64 + lane], w1, acc);
    }
    if (e < end) {
        int s0 = csr[e];
        acc = fmaf(h1[(size_t)s0 * 64 + lane], dinv[s0] * di, acc);
    }

    float g = fmaxf(acc + b1[lane], 0.f);

    float v0 = g * W2[lane * 3 + 0];
    float v1 = g * W2[lane * 3 + 1];
    float v2 = g * W2[lane * 3 + 2];
#pragma unroll
    for (int off = 32; off > 0; off >>= 1) {
        v0 += __shfl_xor(v0, off, 64);
        v1 += __shfl_xor(v1, off, 64);
        v2 += __shfl_xor(v2, off, 64);
    }
    if (lane == 0) h2[node] = make_float4(v0, v1, v2, 0.f);
}

// ---------- agg2: out = A_norm h2 + b2, [N,3] ----------
// One wave per node, lanes parallel over edges (avg deg ~32 -> usually 1 pass).
__global__ __launch_bounds__(256) void k_agg2(const float4* __restrict__ h2,
                                              const int* __restrict__ csr,
                                              const int* __restrict__ offsets,
                                              const float* __restrict__ dinv,
                                              const float* __restrict__ b2,
                                              float* __restrict__ out, int N) {
    int t = threadIdx.x;
    int lane = t & 63;
    int node = blockIdx.x * 4 + (t >> 6);
    if (node >= N) return;

    float di = dinv[node];
    int beg = offsets[node], end = offsets[node + 1];
    float a0 = 0.f, a1 = 0.f, a2 = 0.f;
    for (int e = beg + lane; e < end; e += 64) {
        int s = csr[e];
        float w = dinv[s] * di;
        float4 h = h2[s];
        a0 = fmaf(h.x, w, a0);
        a1 = fmaf(h.y, w, a1);
        a2 = fmaf(h.z, w, a2);
    }
#pragma unroll
    for (int off = 32; off > 0; off >>= 1) {
        a0 += __shfl_xor(a0, off, 64);
        a1 += __shfl_xor(a1, off, 64);
        a2 += __shfl_xor(a2, off, 64);
    }
    if (lane == 0) {
        float4 hs = h2[node];
        float sl = di * di;
        out[(size_t)node * 3 + 0] = a0 + hs.x * sl + b2[0];
        out[(size_t)node * 3 + 1] = a1 + hs.y * sl + b2[1];
        out[(size_t)node * 3 + 2] = a2 + hs.z * sl + b2[2];
    }
}

extern "C" void kernel_launch(void* const* d_in, const int* in_sizes, int n_in,
                              void* d_out, int out_size, void* d_ws, size_t ws_size,
                              hipStream_t stream) {
    const float* x = (const float*)d_in[0];
    const int* eidx = (const int*)d_in[1];
    const float* W1 = (const float*)d_in[2];
    const float* b1 = (const float*)d_in[3];
    const float* W2 = (const float*)d_in[4];
    const float* b2 = (const float*)d_in[5];
    float* out = (float*)d_out;

    const int N = in_sizes[0] / DIM_IN;   // 100000
    const int E = in_sizes[1] / 2;        // 3200000

    // workspace carve-out (~42 MB), 256B-aligned slices; fully rewritten each call
    char* w = (char*)d_ws;
    size_t off = 0;
    auto carve = [&](size_t bytes) -> char* {
        char* p = w + off;
        off += (bytes + 255) & ~(size_t)255;
        return p;
    };
    int* flag = (int*)carve(16);
    int* cnt = (int*)carve((size_t)N * 4);
    int* offsets = (int*)carve((size_t)(N + 1) * 4);
    int* cursor = (int*)carve((size_t)N * 4);
    int* bsum = (int*)carve(1024 * 4);
    float* dinv = (float*)carve((size_t)N * 4);
    int* csr = (int*)carve((size_t)E * 4);
    float* h1 = (float*)carve((size_t)N * DIM_HID * 4);
    float4* h2 = (float4*)carve((size_t)N * 16);

    hipMemsetAsync(cnt, 0, (size_t)N * 4, stream);
    k_detect<<<1, 64, 0, stream>>>(eidx, flag);

    int eb = (E + 255) / 256;
    k_count<<<eb, 256, 0, stream>>>(eidx, flag, cnt, E);

    int NB = (N + 1023) / 1024;
    k_s1<<<NB, 1024, 0, stream>>>(cnt, dinv, bsum, N);
    k_s2<<<1, 64, 0, stream>>>(bsum, NB);
    k_s3<<<NB, 1024, 0, stream>>>(cnt, bsum, offsets, cursor, N);
    k_fill<<<eb, 256, 0, stream>>>(eidx, flag, cursor, csr, E);

    k_gemm1<<<(N + 15) / 16, 256, 0, stream>>>(x, W1, h1, N);
    k_agg1<<<(N + 3) / 4, 256, 0, stream>>>(h1, csr, offsets, dinv, b1, W2, h2, N);
    k_agg2<<<(N + 3) / 4, 256, 0, stream>>>(h2, csr, offsets, dinv, b2, out, N);
}

// Round 2
// 510.872 us; speedup vs baseline: 1.4429x; 1.4429x over previous
//
#include <hip/hip_runtime.h>
#include <cstdint>
#include <cstddef>

#define DIM_IN 128
#define DIM_HID 64
#define FILL_GPB 256   // blocks per dst-partition group in k_fillp

// ---------- edge dtype detection: int32 (stride 1) vs int64 (stride 2) ----------
__global__ void k_detect(const int* __restrict__ e, int* __restrict__ flag) {
    if (blockIdx.x == 0 && threadIdx.x == 0) {
        int o = 0;
        for (int j = 1; j < 128; j += 2) o |= e[j];
        flag[0] = (o == 0) ? 2 : 1;
    }
}

// ---------- compact int64->int32 src/dst arrays + fused degree histogram ----------
__global__ __launch_bounds__(256) void k_compact(const int* __restrict__ eidx,
                                                 const int* __restrict__ flag,
                                                 int* __restrict__ src32,
                                                 int* __restrict__ dst32,
                                                 int* __restrict__ cnt, int E) {
    int i = (blockIdx.x * 256 + threadIdx.x) * 4;
    if (i >= E) return;
    int st = flag[0];
    if (i + 3 < E && ((E & 1) == 0 || st == 1)) {
        int4 s, d;
        if (st == 2) {
            const int4* p = (const int4*)eidx;
            int4 a = p[i >> 1], b = p[(i >> 1) + 1];
            int4 c = p[(E + i) >> 1], f = p[((E + i) >> 1) + 1];
            s = make_int4(a.x, a.z, b.x, b.z);
            d = make_int4(c.x, c.z, f.x, f.z);
        } else {
            s = ((const int4*)eidx)[i >> 2];
            d = ((const int4*)(eidx + E))[i >> 2];
        }
        ((int4*)src32)[i >> 2] = s;
        ((int4*)dst32)[i >> 2] = d;
        atomicAdd(&cnt[d.x], 1);
        atomicAdd(&cnt[d.y], 1);
        atomicAdd(&cnt[d.z], 1);
        atomicAdd(&cnt[d.w], 1);
    } else {
        for (int j = i; j < E; j++) {
            int s = eidx[(size_t)j * st];
            int d = eidx[(size_t)(E + j) * st];
            src32[j] = s;
            dst32[j] = d;
            atomicAdd(&cnt[d], 1);
        }
    }
}

// ---------- scan S1: per-1024-chunk sums; also dinv = rsqrt(cnt+1) ----------
__global__ __launch_bounds__(1024) void k_s1(const int* __restrict__ cnt,
                                             float* __restrict__ dinv,
                                             int* __restrict__ bsum, int N) {
    __shared__ int sh[1024];
    int t = threadIdx.x;
    int i = blockIdx.x * 1024 + t;
    int c = (i < N) ? cnt[i] : 0;
    if (i < N) dinv[i] = rsqrtf((float)(c + 1));
    sh[t] = c;
    __syncthreads();
    for (int d = 512; d > 0; d >>= 1) {
        if (t < d) sh[t] += sh[t + d];
        __syncthreads();
    }
    if (t == 0) bsum[blockIdx.x] = sh[0];
}

__global__ void k_s2(int* __restrict__ bsum, int NB) {
    if (blockIdx.x == 0 && threadIdx.x == 0) {
        int run = 0;
        for (int b = 0; b < NB; b++) { int v = bsum[b]; bsum[b] = run; run += v; }
    }
}

__global__ __launch_bounds__(1024) void k_s3(const int* __restrict__ cnt,
                                             const int* __restrict__ bsum,
                                             int* __restrict__ offsets,
                                             int* __restrict__ cursor, int N) {
    __shared__ int sh[1024];
    int t = threadIdx.x;
    int i = blockIdx.x * 1024 + t;
    int c = (i < N) ? cnt[i] : 0;
    sh[t] = c;
    __syncthreads();
    for (int d = 1; d < 1024; d <<= 1) {
        int add = (t >= d) ? sh[t - d] : 0;
        __syncthreads();
        sh[t] += add;
        __syncthreads();
    }
    if (i < N) {
        int incl = bsum[blockIdx.x] + sh[t];
        offsets[i + 1] = incl;
        cursor[i] = incl - c;
    }
    if (i == 0) offsets[0] = 0;
}

// ---------- CSR fill, XCD-partitioned by dst range ----------
// 8 groups; p = blockIdx.x & 7 rides round-robin block->XCD dispatch so each
// XCD's L2 owns one 1.6MB csr slice -> lines fill completely before eviction.
__global__ __launch_bounds__(256) void k_fillp(const int* __restrict__ src32,
                                               const int* __restrict__ dst32,
                                               int* __restrict__ cursor,
                                               int* __restrict__ csr,
                                               int E, int N) {
    int p = blockIdx.x & 7;
    int g = blockIdx.x >> 3;
    int rng = (N + 7) >> 3;
    int lo = p * rng;
    int hi = min(lo + rng, N);

    for (int base = g * 1024 + threadIdx.x * 4; base < E; base += FILL_GPB * 1024) {
        if (base + 3 < E) {
            int4 s = ((const int4*)src32)[base >> 2];
            int4 d = ((const int4*)dst32)[base >> 2];
            if (d.x >= lo && d.x < hi) { int q = atomicAdd(&cursor[d.x], 1); csr[q] = s.x; }
            if (d.y >= lo && d.y < hi) { int q = atomicAdd(&cursor[d.y], 1); csr[q] = s.y; }
            if (d.z >= lo && d.z < hi) { int q = atomicAdd(&cursor[d.z], 1); csr[q] = s.z; }
            if (d.w >= lo && d.w < hi) { int q = atomicAdd(&cursor[d.w], 1); csr[q] = s.w; }
        } else {
            for (int j = base; j < E; j++) {
                int dd = dst32[j];
                if (dd >= lo && dd < hi) { int q = atomicAdd(&cursor[dd], 1); csr[q] = src32[j]; }
            }
        }
    }
}

// ---------- GEMM1: h1 = x @ W1, [N,128]x[128,64] fp32 ----------
__global__ __launch_bounds__(256) void k_gemm1(const float* __restrict__ x,
                                               const float* __restrict__ W,
                                               float* __restrict__ h1, int N) {
    __shared__ float Ws[DIM_IN * DIM_HID];
    int t = threadIdx.x;
#pragma unroll
    for (int i = 0; i < 8; i++)
        ((float4*)Ws)[t + 256 * i] = ((const float4*)W)[t + 256 * i];
    __syncthreads();

    int col = t & 63;
    int rg = __builtin_amdgcn_readfirstlane(t >> 6);
    int row0 = blockIdx.x * 16 + rg * 4;
    if (row0 >= N) return;

    const float* xr = x + (size_t)row0 * DIM_IN;
    float a0 = 0.f, a1 = 0.f, a2 = 0.f, a3 = 0.f;
#pragma unroll 4
    for (int k = 0; k < DIM_IN; k++) {
        float w = Ws[k * DIM_HID + col];
        a0 = fmaf(xr[k], w, a0);
        a1 = fmaf(xr[DIM_IN + k], w, a1);
        a2 = fmaf(xr[2 * DIM_IN + k], w, a2);
        a3 = fmaf(xr[3 * DIM_IN + k], w, a3);
    }
    size_t o = (size_t)row0 * DIM_HID + col;
    h1[o] = a0;
    h1[o + DIM_HID] = a1;
    h1[o + 2 * DIM_HID] = a2;
    h1[o + 3 * DIM_HID] = a3;
}

// ---------- agg1 fused: g = relu(A_norm h1 + b1); h2 = g @ W2 ----------
__global__ __launch_bounds__(256) void k_agg1(const float* __restrict__ h1,
                                              const int* __restrict__ csr,
                                              const int* __restrict__ offsets,
                                              const float* __restrict__ dinv,
                                              const float* __restrict__ b1,
                                              const float* __restrict__ W2,
                                              float4* __restrict__ h2, int N) {
    int t = threadIdx.x;
    int lane = t & 63;
    int node = blockIdx.x * 4 + (t >> 6);
    if (node >= N) return;

    float di = dinv[node];
    int beg = offsets[node], end = offsets[node + 1];
    float acc = h1[(size_t)node * 64 + lane] * di * di;  // self-loop

    int e = beg;
    for (; e + 3 < end; e += 4) {
        int s0 = csr[e], s1 = csr[e + 1], s2 = csr[e + 2], s3 = csr[e + 3];
        float w0 = dinv[s0] * di, w1 = dinv[s1] * di;
        float w2 = dinv[s2] * di, w3 = dinv[s3] * di;
        acc = fmaf(h1[(size_t)s0 * 64 + lane], w0, acc);
        acc = fmaf(h1[(size_t)s1 * 64 + lane], w1, acc);
        acc = fmaf(h1[(size_t)s2 * 64 + lane], w2, acc);
        acc = fmaf(h1[(size_t)s3 * 64 + lane], w3, acc);
    }
    for (; e < end; e++) {
        int s0 = csr[e];
        acc = fmaf(h1[(size_t)s0 * 64 + lane], dinv[s0] * di, acc);
    }

    float g = fmaxf(acc + b1[lane], 0.f);

    float v0 = g * W2[lane * 3 + 0];
    float v1 = g * W2[lane * 3 + 1];
    float v2 = g * W2[lane * 3 + 2];
#pragma unroll
    for (int off = 32; off > 0; off >>= 1) {
        v0 += __shfl_xor(v0, off, 64);
        v1 += __shfl_xor(v1, off, 64);
        v2 += __shfl_xor(v2, off, 64);
    }
    if (lane == 0) h2[node] = make_float4(v0, v1, v2, 0.f);
}

// ---------- agg2: out = A_norm h2 + b2, [N,3] ----------
__global__ __launch_bounds__(256) void k_agg2(const float4* __restrict__ h2,
                                              const int* __restrict__ csr,
                                              const int* __restrict__ offsets,
                                              const float* __restrict__ dinv,
                                              const float* __restrict__ b2,
                                              float* __restrict__ out, int N) {
    int t = threadIdx.x;
    int lane = t & 63;
    int node = blockIdx.x * 4 + (t >> 6);
    if (node >= N) return;

    float di = dinv[node];
    int beg = offsets[node], end = offsets[node + 1];
    float a0 = 0.f, a1 = 0.f, a2 = 0.f;
    for (int e = beg + lane; e < end; e += 64) {
        int s = csr[e];
        float w = dinv[s] * di;
        float4 h = h2[s];
        a0 = fmaf(h.x, w, a0);
        a1 = fmaf(h.y, w, a1);
        a2 = fmaf(h.z, w, a2);
    }
#pragma unroll
    for (int off = 32; off > 0; off >>= 1) {
        a0 += __shfl_xor(a0, off, 64);
        a1 += __shfl_xor(a1, off, 64);
        a2 += __shfl_xor(a2, off, 64);
    }
    if (lane == 0) {
        float4 hs = h2[node];
        float sl = di * di;
        out[(size_t)node * 3 + 0] = a0 + hs.x * sl + b2[0];
        out[(size_t)node * 3 + 1] = a1 + hs.y * sl + b2[1];
        out[(size_t)node * 3 + 2] = a2 + hs.z * sl + b2[2];
    }
}

extern "C" void kernel_launch(void* const* d_in, const int* in_sizes, int n_in,
                              void* d_out, int out_size, void* d_ws, size_t ws_size,
                              hipStream_t stream) {
    const float* x = (const float*)d_in[0];
    const int* eidx = (const int*)d_in[1];
    const float* W1 = (const float*)d_in[2];
    const float* b1 = (const float*)d_in[3];
    const float* W2 = (const float*)d_in[4];
    const float* b2 = (const float*)d_in[5];
    float* out = (float*)d_out;

    const int N = in_sizes[0] / DIM_IN;   // 100000
    const int E = in_sizes[1] / 2;        // 3200000

    // workspace carve-out (~42 MB); h1 aliases src32/dst32 (dead after fill)
    char* w = (char*)d_ws;
    size_t off = 0;
    auto carve = [&](size_t bytes) -> char* {
        char* p = w + off;
        off += (bytes + 255) & ~(size_t)255;
        return p;
    };
    int* flag = (int*)carve(16);
    int* cnt = (int*)carve((size_t)N * 4);
    int* offsets = (int*)carve((size_t)(N + 1) * 4);
    int* cursor = (int*)carve((size_t)N * 4);
    int* bsum = (int*)carve(1024 * 4);
    float* dinv = (float*)carve((size_t)N * 4);
    int* csr = (int*)carve((size_t)E * 4);
    char* uni = carve((size_t)E * 8 > (size_t)N * DIM_HID * 4 ? (size_t)E * 8
                                                              : (size_t)N * DIM_HID * 4);
    int* src32 = (int*)uni;
    int* dst32 = (int*)(uni + (size_t)E * 4);
    float* h1 = (float*)uni;              // aliased: valid only after k_fillp
    float4* h2 = (float4*)carve((size_t)N * 16);

    hipMemsetAsync(cnt, 0, (size_t)N * 4, stream);
    k_detect<<<1, 64, 0, stream>>>(eidx, flag);

    int cb = (E + 1023) / 1024;
    k_compact<<<cb, 256, 0, stream>>>(eidx, flag, src32, dst32, cnt, E);

    int NB = (N + 1023) / 1024;
    k_s1<<<NB, 1024, 0, stream>>>(cnt, dinv, bsum, N);
    k_s2<<<1, 64, 0, stream>>>(bsum, NB);
    k_s3<<<NB, 1024, 0, stream>>>(cnt, bsum, offsets, cursor, N);

    k_fillp<<<8 * FILL_GPB, 256, 0, stream>>>(src32, dst32, cursor, csr, E, N);

    k_gemm1<<<(N + 15) / 16, 256, 0, stream>>>(x, W1, h1, N);
    k_agg1<<<(N + 3) / 4, 256, 0, stream>>>(h1, csr, offsets, dinv, b1, W2, h2, N);
    k_agg2<<<(N + 3) / 4, 256, 0, stream>>>(h2, csr, offsets, dinv, b2, out, N);
}

// Round 4
// 508.116 us; speedup vs baseline: 1.4508x; 1.0054x over previous
//
#include <hip/hip_runtime.h>
#include <cstdint>
#include <cstddef>

#define DIM_IN 128
#define DIM_HID 64
#define FILL_GPB 256   // blocks per dst-partition group in k_fillp

// native clang vector (nontemporal builtins reject HIP_vector_type classes)
typedef int v4i __attribute__((ext_vector_type(4)));

// ---------- edge dtype detection: int32 (stride 1) vs int64 (stride 2) ----------
__global__ void k_detect(const int* __restrict__ e, int* __restrict__ flag) {
    if (blockIdx.x == 0 && threadIdx.x == 0) {
        int o = 0;
        for (int j = 1; j < 128; j += 2) o |= e[j];
        flag[0] = (o == 0) ? 2 : 1;
    }
}

// ---------- compact int64->int32 src/dst arrays + fused degree histogram ----------
// eidx reads are single-use -> non-temporal (don't thrash L2/L3 for cnt atomics).
__global__ __launch_bounds__(256) void k_compact(const int* __restrict__ eidx,
                                                 const int* __restrict__ flag,
                                                 int* __restrict__ src32,
                                                 int* __restrict__ dst32,
                                                 int* __restrict__ cnt, int E) {
    int i = (blockIdx.x * 256 + threadIdx.x) * 4;
    if (i >= E) return;
    int st = flag[0];
    if (i + 3 < E && ((E & 1) == 0 || st == 1)) {
        v4i s, d;
        if (st == 2) {
            const v4i* p = (const v4i*)eidx;
            v4i a = __builtin_nontemporal_load(p + (i >> 1));
            v4i b = __builtin_nontemporal_load(p + (i >> 1) + 1);
            v4i c = __builtin_nontemporal_load(p + ((E + i) >> 1));
            v4i f = __builtin_nontemporal_load(p + ((E + i) >> 1) + 1);
            s = (v4i){a.x, a.z, b.x, b.z};
            d = (v4i){c.x, c.z, f.x, f.z};
        } else {
            s = __builtin_nontemporal_load((const v4i*)eidx + (i >> 2));
            d = __builtin_nontemporal_load((const v4i*)(eidx + E) + (i >> 2));
        }
        ((v4i*)src32)[i >> 2] = s;
        ((v4i*)dst32)[i >> 2] = d;
        atomicAdd(&cnt[d.x], 1);
        atomicAdd(&cnt[d.y], 1);
        atomicAdd(&cnt[d.z], 1);
        atomicAdd(&cnt[d.w], 1);
    } else {
        for (int j = i; j < E; j++) {
            int s = eidx[(size_t)j * st];
            int d = eidx[(size_t)(E + j) * st];
            src32[j] = s;
            dst32[j] = d;
            atomicAdd(&cnt[d], 1);
        }
    }
}

// ---------- scan S1: per-1024-chunk sums; also dinv = rsqrt(cnt+1) ----------
__global__ __launch_bounds__(1024) void k_s1(const int* __restrict__ cnt,
                                             float* __restrict__ dinv,
                                             int* __restrict__ bsum, int N) {
    __shared__ int sh[1024];
    int t = threadIdx.x;
    int i = blockIdx.x * 1024 + t;
    int c = (i < N) ? cnt[i] : 0;
    if (i < N) dinv[i] = rsqrtf((float)(c + 1));
    sh[t] = c;
    __syncthreads();
    for (int d = 512; d > 0; d >>= 1) {
        if (t < d) sh[t] += sh[t + d];
        __syncthreads();
    }
    if (t == 0) bsum[blockIdx.x] = sh[0];
}

__global__ void k_s2(int* __restrict__ bsum, int NB) {
    if (blockIdx.x == 0 && threadIdx.x == 0) {
        int run = 0;
        for (int b = 0; b < NB; b++) { int v = bsum[b]; bsum[b] = run; run += v; }
    }
}

__global__ __launch_bounds__(1024) void k_s3(const int* __restrict__ cnt,
                                             const int* __restrict__ bsum,
                                             int* __restrict__ offsets,
                                             int* __restrict__ cursor, int N) {
    __shared__ int sh[1024];
    int t = threadIdx.x;
    int i = blockIdx.x * 1024 + t;
    int c = (i < N) ? cnt[i] : 0;
    sh[t] = c;
    __syncthreads();
    for (int d = 1; d < 1024; d <<= 1) {
        int add = (t >= d) ? sh[t - d] : 0;
        __syncthreads();
        sh[t] += add;
        __syncthreads();
    }
    if (i < N) {
        int incl = bsum[blockIdx.x] + sh[t];
        offsets[i + 1] = incl;
        cursor[i] = incl - c;
    }
    if (i == 0) offsets[0] = 0;
}

// ---------- CSR fill, XCD-partitioned by dst range ----------
// 8 groups; p = blockIdx.x & 7 rides round-robin block->XCD dispatch so each
// XCD's L2 owns one 1.6MB csr slice. Streaming src/dst reads are NON-TEMPORAL
// so they don't evict the partially-filled csr lines (R2 post-mortem: normal
// loads thrashed L2 -> WRITE_SIZE stayed 175MB).
__global__ __launch_bounds__(256) void k_fillp(const int* __restrict__ src32,
                                               const int* __restrict__ dst32,
                                               int* __restrict__ cursor,
                                               int* __restrict__ csr,
                                               int E, int N) {
    int p = blockIdx.x & 7;
    int g = blockIdx.x >> 3;
    int rng = (N + 7) >> 3;
    int lo = p * rng;
    int hi = min(lo + rng, N);

    for (int base = g * 1024 + threadIdx.x * 4; base < E; base += FILL_GPB * 1024) {
        if (base + 3 < E) {
            v4i s = __builtin_nontemporal_load((const v4i*)src32 + (base >> 2));
            v4i d = __builtin_nontemporal_load((const v4i*)dst32 + (base >> 2));
            if (d.x >= lo && d.x < hi) { int q = atomicAdd(&cursor[d.x], 1); csr[q] = s.x; }
            if (d.y >= lo && d.y < hi) { int q = atomicAdd(&cursor[d.y], 1); csr[q] = s.y; }
            if (d.z >= lo && d.z < hi) { int q = atomicAdd(&cursor[d.z], 1); csr[q] = s.z; }
            if (d.w >= lo && d.w < hi) { int q = atomicAdd(&cursor[d.w], 1); csr[q] = s.w; }
        } else {
            for (int j = base; j < E; j++) {
                int dd = dst32[j];
                if (dd >= lo && dd < hi) { int q = atomicAdd(&cursor[dd], 1); csr[q] = src32[j]; }
            }
        }
    }
}

// ---------- GEMM1: h1 = x @ W1, [N,128]x[128,64] fp32 ----------
__global__ __launch_bounds__(256) void k_gemm1(const float* __restrict__ x,
                                               const float* __restrict__ W,
                                               float* __restrict__ h1, int N) {
    __shared__ float Ws[DIM_IN * DIM_HID];
    int t = threadIdx.x;
#pragma unroll
    for (int i = 0; i < 8; i++)
        ((float4*)Ws)[t + 256 * i] = ((const float4*)W)[t + 256 * i];
    __syncthreads();

    int col = t & 63;
    int rg = __builtin_amdgcn_readfirstlane(t >> 6);
    int row0 = blockIdx.x * 16 + rg * 4;
    if (row0 >= N) return;

    const float* xr = x + (size_t)row0 * DIM_IN;
    float a0 = 0.f, a1 = 0.f, a2 = 0.f, a3 = 0.f;
#pragma unroll 4
    for (int k = 0; k < DIM_IN; k++) {
        float w = Ws[k * DIM_HID + col];
        a0 = fmaf(xr[k], w, a0);
        a1 = fmaf(xr[DIM_IN + k], w, a1);
        a2 = fmaf(xr[2 * DIM_IN + k], w, a2);
        a3 = fmaf(xr[3 * DIM_IN + k], w, a3);
    }
    size_t o = (size_t)row0 * DIM_HID + col;
    h1[o] = a0;
    h1[o + DIM_HID] = a1;
    h1[o + 2 * DIM_HID] = a2;
    h1[o + 3 * DIM_HID] = a3;
}

// ---------- agg1 fused: g = relu(A_norm h1 + b1); h2 = g @ W2 ----------
__global__ __launch_bounds__(256) void k_agg1(const float* __restrict__ h1,
                                              const int* __restrict__ csr,
                                              const int* __restrict__ offsets,
                                              const float* __restrict__ dinv,
                                              const float* __restrict__ b1,
                                              const float* __restrict__ W2,
                                              float4* __restrict__ h2, int N) {
    int t = threadIdx.x;
    int lane = t & 63;
    int node = blockIdx.x * 4 + (t >> 6);
    if (node >= N) return;

    float di = dinv[node];
    int beg = offsets[node], end = offsets[node + 1];
    float acc = h1[(size_t)node * 64 + lane] * di * di;  // self-loop

    int e = beg;
    for (; e + 3 < end; e += 4) {
        int s0 = csr[e], s1 = csr[e + 1], s2 = csr[e + 2], s3 = csr[e + 3];
        float w0 = dinv[s0] * di, w1 = dinv[s1] * di;
        float w2 = dinv[s2] * di, w3 = dinv[s3] * di;
        acc = fmaf(h1[(size_t)s0 * 64 + lane], w0, acc);
        acc = fmaf(h1[(size_t)s1 * 64 + lane], w1, acc);
        acc = fmaf(h1[(size_t)s2 * 64 + lane], w2, acc);
        acc = fmaf(h1[(size_t)s3 * 64 + lane], w3, acc);
    }
    for (; e < end; e++) {
        int s0 = csr[e];
        acc = fmaf(h1[(size_t)s0 * 64 + lane], dinv[s0] * di, acc);
    }

    float g = fmaxf(acc + b1[lane], 0.f);

    float v0 = g * W2[lane * 3 + 0];
    float v1 = g * W2[lane * 3 + 1];
    float v2 = g * W2[lane * 3 + 2];
#pragma unroll
    for (int off = 32; off > 0; off >>= 1) {
        v0 += __shfl_xor(v0, off, 64);
        v1 += __shfl_xor(v1, off, 64);
        v2 += __shfl_xor(v2, off, 64);
    }
    if (lane == 0) h2[node] = make_float4(v0, v1, v2, 0.f);
}

// ---------- agg2: out = A_norm h2 + b2, [N,3] ----------
__global__ __launch_bounds__(256) void k_agg2(const float4* __restrict__ h2,
                                              const int* __restrict__ csr,
                                              const int* __restrict__ offsets,
                                              const float* __restrict__ dinv,
                                              const float* __restrict__ b2,
                                              float* __restrict__ out, int N) {
    int t = threadIdx.x;
    int lane = t & 63;
    int node = blockIdx.x * 4 + (t >> 6);
    if (node >= N) return;

    float di = dinv[node];
    int beg = offsets[node], end = offsets[node + 1];
    float a0 = 0.f, a1 = 0.f, a2 = 0.f;
    for (int e = beg + lane; e < end; e += 64) {
        int s = csr[e];
        float w = dinv[s] * di;
        float4 h = h2[s];
        a0 = fmaf(h.x, w, a0);
        a1 = fmaf(h.y, w, a1);
        a2 = fmaf(h.z, w, a2);
    }
#pragma unroll
    for (int off = 32; off > 0; off >>= 1) {
        a0 += __shfl_xor(a0, off, 64);
        a1 += __shfl_xor(a1, off, 64);
        a2 += __shfl_xor(a2, off, 64);
    }
    if (lane == 0) {
        float4 hs = h2[node];
        float sl = di * di;
        out[(size_t)node * 3 + 0] = a0 + hs.x * sl + b2[0];
        out[(size_t)node * 3 + 1] = a1 + hs.y * sl + b2[1];
        out[(size_t)node * 3 + 2] = a2 + hs.z * sl + b2[2];
    }
}

extern "C" void kernel_launch(void* const* d_in, const int* in_sizes, int n_in,
                              void* d_out, int out_size, void* d_ws, size_t ws_size,
                              hipStream_t stream) {
    const float* x = (const float*)d_in[0];
    const int* eidx = (const int*)d_in[1];
    const float* W1 = (const float*)d_in[2];
    const float* b1 = (const float*)d_in[3];
    const float* W2 = (const float*)d_in[4];
    const float* b2 = (const float*)d_in[5];
    float* out = (float*)d_out;

    const int N = in_sizes[0] / DIM_IN;   // 100000
    const int E = in_sizes[1] / 2;        // 3200000

    // workspace carve-out (~42 MB); h1 aliases src32/dst32 (dead after fill)
    char* w = (char*)d_ws;
    size_t off = 0;
    auto carve = [&](size_t bytes) -> char* {
        char* p = w + off;
        off += (bytes + 255) & ~(size_t)255;
        return p;
    };
    int* flag = (int*)carve(16);
    int* cnt = (int*)carve((size_t)N * 4);
    int* offsets = (int*)carve((size_t)(N + 1) * 4);
    int* cursor = (int*)carve((size_t)N * 4);
    int* bsum = (int*)carve(1024 * 4);
    float* dinv = (float*)carve((size_t)N * 4);
    int* csr = (int*)carve((size_t)E * 4);
    char* uni = carve((size_t)E * 8 > (size_t)N * DIM_HID * 4 ? (size_t)E * 8
                                                              : (size_t)N * DIM_HID * 4);
    int* src32 = (int*)uni;
    int* dst32 = (int*)(uni + (size_t)E * 4);
    float* h1 = (float*)uni;              // aliased: valid only after k_fillp
    float4* h2 = (float4*)carve((size_t)N * 16);

    (void)hipMemsetAsync(cnt, 0, (size_t)N * 4, stream);
    k_detect<<<1, 64, 0, stream>>>(eidx, flag);

    int cb = (E + 1023) / 1024;
    k_compact<<<cb, 256, 0, stream>>>(eidx, flag, src32, dst32, cnt, E);

    int NB = (N + 1023) / 1024;
    k_s1<<<NB, 1024, 0, stream>>>(cnt, dinv, bsum, N);
    k_s2<<<1, 64, 0, stream>>>(bsum, NB);
    k_s3<<<NB, 1024, 0, stream>>>(cnt, bsum, offsets, cursor, N);

    k_fillp<<<8 * FILL_GPB, 256, 0, stream>>>(src32, dst32, cursor, csr, E, N);

    k_gemm1<<<(N + 15) / 16, 256, 0, stream>>>(x, W1, h1, N);
    k_agg1<<<(N + 3) / 4, 256, 0, stream>>>(h1, csr, offsets, dinv, b1, W2, h2, N);
    k_agg2<<<(N + 3) / 4, 256, 0, stream>>>(h2, csr, offsets, dinv, b2, out, N);
}

// Round 5
// 503.663 us; speedup vs baseline: 1.4636x; 1.0088x over previous
//
#include <hip/hip_runtime.h>
#include <cstdint>
#include <cstddef>

#define DIM_IN 128
#define DIM_HID 64
#define MS_TILE 2048      // edges per multisplit tile
#define MS_WGS 512        // msplit workgroups
#define GPB2 8            // workgroups per bin in k_fillp2
#define OVF_CAP 32768     // overflow valve capacity (edges)

// native clang vectors (nontemporal builtins reject HIP_vector_type classes)
typedef int v2i __attribute__((ext_vector_type(2)));

// ---------- edge dtype detection: int32 (stride 1) vs int64 (stride 2) ----------
__global__ void k_detect(const int* __restrict__ e, int* __restrict__ flag) {
    if (blockIdx.x == 0 && threadIdx.x == 0) {
        int o = 0;
        for (int j = 1; j < 128; j += 2) o |= e[j];
        flag[0] = (o == 0) ? 2 : 1;
    }
}

// ---------- multisplit: eidx -> 98 dst-bins of (src,dst) pairs + degree cnt ----------
// Tile counting-sort in LDS -> contiguous ~168B runs per bin per tile (dense
// writes; kills the 10x scatter write-amp seen in k_fillp R1-R4).
__global__ __launch_bounds__(256) void k_msplit(const int* __restrict__ eidx,
                                                const int* __restrict__ flag,
                                                int* __restrict__ cnt,
                                                int* __restrict__ binCursor,
                                                v2i* __restrict__ binned,
                                                int* __restrict__ ovfCnt,
                                                v2i* __restrict__ ovf,
                                                int E, int NB, int cap) {
    __shared__ int hist[128], base[128], scanb[128];
    __shared__ v2i buf[MS_TILE];
    int t = threadIdx.x;
    int st = flag[0];
    int ntiles = (E + MS_TILE - 1) / MS_TILE;

    for (int tile = blockIdx.x; tile < ntiles; tile += gridDim.x) {
        int e0 = tile * MS_TILE;
        int cntE = min(MS_TILE, E - e0);

        int srcs[8], dsts[8], bins[8];
#pragma unroll
        for (int j = 0; j < 8; j++) {
            int e = e0 + t + 256 * j;
            if (e < E) {
                srcs[j] = __builtin_nontemporal_load(&eidx[(size_t)e * st]);
                dsts[j] = __builtin_nontemporal_load(&eidx[(size_t)(E + e) * st]);
                bins[j] = dsts[j] >> 10;
                atomicAdd(&cnt[dsts[j]], 1);
            } else {
                bins[j] = -1;
            }
        }

        if (t < 128) hist[t] = 0;
        __syncthreads();
#pragma unroll
        for (int j = 0; j < 8; j++)
            if (bins[j] >= 0) atomicAdd(&hist[bins[j]], 1);
        __syncthreads();
        if (t == 0) {               // tiny serial scan over <=128 bins
            int run = 0;
            for (int b = 0; b < NB; b++) { scanb[b] = run; run += hist[b]; }
        }
        __syncthreads();
        if (t < NB && hist[t] > 0) base[t] = atomicAdd(&binCursor[t], hist[t]);
        __syncthreads();
        if (t < 128) hist[t] = 0;   // reuse as rank counters
        __syncthreads();
#pragma unroll
        for (int j = 0; j < 8; j++) {
            if (bins[j] >= 0) {
                int r = atomicAdd(&hist[bins[j]], 1);
                buf[scanb[bins[j]] + r] = (v2i){srcs[j], dsts[j]};
            }
        }
        __syncthreads();
        for (int j = t; j < cntE; j += 256) {
            v2i p = buf[j];
            int b = p.y >> 10;
            int local = base[b] + (j - scanb[b]);
            if (local < cap) {
                binned[(size_t)b * cap + local] = p;
            } else {
                int o = atomicAdd(ovfCnt, 1);
                if (o < OVF_CAP) ovf[o] = p;
            }
        }
        __syncthreads();
    }
}

// ---------- scan S1: per-1024-chunk sums; also dinv = rsqrt(cnt+1) ----------
__global__ __launch_bounds__(1024) void k_s1(const int* __restrict__ cnt,
                                             float* __restrict__ dinv,
                                             int* __restrict__ bsum, int N) {
    __shared__ int sh[1024];
    int t = threadIdx.x;
    int i = blockIdx.x * 1024 + t;
    int c = (i < N) ? cnt[i] : 0;
    if (i < N) dinv[i] = rsqrtf((float)(c + 1));
    sh[t] = c;
    __syncthreads();
    for (int d = 512; d > 0; d >>= 1) {
        if (t < d) sh[t] += sh[t + d];
        __syncthreads();
    }
    if (t == 0) bsum[blockIdx.x] = sh[0];
}

__global__ void k_s2(int* __restrict__ bsum, int NB) {
    if (blockIdx.x == 0 && threadIdx.x == 0) {
        int run = 0;
        for (int b = 0; b < NB; b++) { int v = bsum[b]; bsum[b] = run; run += v; }
    }
}

__global__ __launch_bounds__(1024) void k_s3(const int* __restrict__ cnt,
                                             const int* __restrict__ bsum,
                                             int* __restrict__ offsets,
                                             int* __restrict__ cursor, int N) {
    __shared__ int sh[1024];
    int t = threadIdx.x;
    int i = blockIdx.x * 1024 + t;
    int c = (i < N) ? cnt[i] : 0;
    sh[t] = c;
    __syncthreads();
    for (int d = 1; d < 1024; d <<= 1) {
        int add = (t >= d) ? sh[t - d] : 0;
        __syncthreads();
        sh[t] += add;
        __syncthreads();
    }
    if (i < N) {
        int incl = bsum[blockIdx.x] + sh[t];
        offsets[i + 1] = incl;
        cursor[i] = incl - c;
    }
    if (i == 0) offsets[0] = 0;
}

// ---------- CSR fill from bins ----------
// One bin's csr window is ~131KB (1024 nodes). All GPB2 WGs of a bin land on
// the SAME XCD (blockIdx%8 ~ XCD round-robin) so the window lives in one L2
// and lines fill completely before eviction.
__global__ __launch_bounds__(256) void k_fillp2(const v2i* __restrict__ binned,
                                                const int* __restrict__ binCursor,
                                                int* __restrict__ cursor,
                                                int* __restrict__ csr,
                                                int cap, int NB) {
    int xcd = blockIdx.x & 7;
    int r = blockIdx.x >> 3;
    int bpx = (NB + 7) >> 3;
    int w = r / bpx;
    int bi = r - w * bpx;
    int b = bi * 8 + xcd;
    if (b >= NB) return;

    int n = min(binCursor[b], cap);
    const v2i* p = binned + (size_t)b * cap;
    for (int i = w * 256 + threadIdx.x; i < n; i += GPB2 * 256) {
        v2i e = __builtin_nontemporal_load(p + i);
        int pos = atomicAdd(&cursor[e.y], 1);
        csr[pos] = e.x;
    }
}

// ---------- drain overflow valve (normally 0 edges) ----------
__global__ void k_ovf(const int* __restrict__ ovfCnt, const v2i* __restrict__ ovf,
                      int* __restrict__ cursor, int* __restrict__ csr) {
    int n = min(*ovfCnt, OVF_CAP);
    for (int i = threadIdx.x; i < n; i += 256) {
        v2i e = ovf[i];
        int pos = atomicAdd(&cursor[e.y], 1);
        csr[pos] = e.x;
    }
}

// ---------- GEMM1: h1 = x @ W1, [N,128]x[128,64] fp32 ----------
__global__ __launch_bounds__(256) void k_gemm1(const float* __restrict__ x,
                                               const float* __restrict__ W,
                                               float* __restrict__ h1, int N) {
    __shared__ float Ws[DIM_IN * DIM_HID];
    int t = threadIdx.x;
#pragma unroll
    for (int i = 0; i < 8; i++)
        ((float4*)Ws)[t + 256 * i] = ((const float4*)W)[t + 256 * i];
    __syncthreads();

    int col = t & 63;
    int rg = __builtin_amdgcn_readfirstlane(t >> 6);
    int row0 = blockIdx.x * 16 + rg * 4;
    if (row0 >= N) return;

    const float* xr = x + (size_t)row0 * DIM_IN;
    float a0 = 0.f, a1 = 0.f, a2 = 0.f, a3 = 0.f;
#pragma unroll 4
    for (int k = 0; k < DIM_IN; k++) {
        float w = Ws[k * DIM_HID + col];
        a0 = fmaf(xr[k], w, a0);
        a1 = fmaf(xr[DIM_IN + k], w, a1);
        a2 = fmaf(xr[2 * DIM_IN + k], w, a2);
        a3 = fmaf(xr[3 * DIM_IN + k], w, a3);
    }
    size_t o = (size_t)row0 * DIM_HID + col;
    h1[o] = a0;
    h1[o + DIM_HID] = a1;
    h1[o + 2 * DIM_HID] = a2;
    h1[o + 3 * DIM_HID] = a3;
}

// ---------- agg1 fused: g = relu(A_norm h1 + b1); h2 = g @ W2 ----------
__global__ __launch_bounds__(256) void k_agg1(const float* __restrict__ h1,
                                              const int* __restrict__ csr,
                                              const int* __restrict__ offsets,
                                              const float* __restrict__ dinv,
                                              const float* __restrict__ b1,
                                              const float* __restrict__ W2,
                                              float4* __restrict__ h2, int N) {
    int t = threadIdx.x;
    int lane = t & 63;
    int node = blockIdx.x * 4 + (t >> 6);
    if (node >= N) return;

    float di = dinv[node];
    int beg = offsets[node], end = offsets[node + 1];
    float acc = h1[(size_t)node * 64 + lane] * di * di;  // self-loop

    int e = beg;
    for (; e + 3 < end; e += 4) {
        int s0 = csr[e], s1 = csr[e + 1], s2 = csr[e + 2], s3 = csr[e + 3];
        float w0 = dinv[s0] * di, w1 = dinv[s1] * di;
        float w2 = dinv[s2] * di, w3 = dinv[s3] * di;
        acc = fmaf(h1[(size_t)s0 * 64 + lane], w0, acc);
        acc = fmaf(h1[(size_t)s1 * 64 + lane], w1, acc);
        acc = fmaf(h1[(size_t)s2 * 64 + lane], w2, acc);
        acc = fmaf(h1[(size_t)s3 * 64 + lane], w3, acc);
    }
    for (; e < end; e++) {
        int s0 = csr[e];
        acc = fmaf(h1[(size_t)s0 * 64 + lane], dinv[s0] * di, acc);
    }

    float g = fmaxf(acc + b1[lane], 0.f);

    float v0 = g * W2[lane * 3 + 0];
    float v1 = g * W2[lane * 3 + 1];
    float v2 = g * W2[lane * 3 + 2];
#pragma unroll
    for (int off = 32; off > 0; off >>= 1) {
        v0 += __shfl_xor(v0, off, 64);
        v1 += __shfl_xor(v1, off, 64);
        v2 += __shfl_xor(v2, off, 64);
    }
    if (lane == 0) h2[node] = make_float4(v0, v1, v2, 0.f);
}

// ---------- agg2: out = A_norm h2 + b2, [N,3] ----------
__global__ __launch_bounds__(256) void k_agg2(const float4* __restrict__ h2,
                                              const int* __restrict__ csr,
                                              const int* __restrict__ offsets,
                                              const float* __restrict__ dinv,
                                              const float* __restrict__ b2,
                                              float* __restrict__ out, int N) {
    int t = threadIdx.x;
    int lane = t & 63;
    int node = blockIdx.x * 4 + (t >> 6);
    if (node >= N) return;

    float di = dinv[node];
    int beg = offsets[node], end = offsets[node + 1];
    float a0 = 0.f, a1 = 0.f, a2 = 0.f;
    for (int e = beg + lane; e < end; e += 64) {
        int s = csr[e];
        float w = dinv[s] * di;
        float4 h = h2[s];
        a0 = fmaf(h.x, w, a0);
        a1 = fmaf(h.y, w, a1);
        a2 = fmaf(h.z, w, a2);
    }
#pragma unroll
    for (int off = 32; off > 0; off >>= 1) {
        a0 += __shfl_xor(a0, off, 64);
        a1 += __shfl_xor(a1, off, 64);
        a2 += __shfl_xor(a2, off, 64);
    }
    if (lane == 0) {
        float4 hs = h2[node];
        float sl = di * di;
        out[(size_t)node * 3 + 0] = a0 + hs.x * sl + b2[0];
        out[(size_t)node * 3 + 1] = a1 + hs.y * sl + b2[1];
        out[(size_t)node * 3 + 2] = a2 + hs.z * sl + b2[2];
    }
}

extern "C" void kernel_launch(void* const* d_in, const int* in_sizes, int n_in,
                              void* d_out, int out_size, void* d_ws, size_t ws_size,
                              hipStream_t stream) {
    const float* x = (const float*)d_in[0];
    const int* eidx = (const int*)d_in[1];
    const float* W1 = (const float*)d_in[2];
    const float* b1 = (const float*)d_in[3];
    const float* W2 = (const float*)d_in[4];
    const float* b2 = (const float*)d_in[5];
    float* out = (float*)d_out;

    const int N = in_sizes[0] / DIM_IN;   // 100000
    const int E = in_sizes[1] / 2;        // 3200000
    const int NB = (N + 1023) >> 10;      // dst bins of 1024 nodes (<=128)

    char* w = (char*)d_ws;
    size_t off = 0;
    auto carve = [&](size_t bytes) -> char* {
        char* p = w + off;
        off += (bytes + 255) & ~(size_t)255;
        return p;
    };
    int* flag = (int*)carve(16);
    int* cnt = (int*)carve((size_t)N * 4);
    int* offsets = (int*)carve((size_t)(N + 1) * 4);
    int* cursor = (int*)carve((size_t)N * 4);
    int* bsum = (int*)carve(1024 * 4);
    float* dinv = (float*)carve((size_t)N * 4);
    int* csr = (int*)carve((size_t)E * 4);
    int* binCursor = (int*)carve(128 * 4);
    int* ovfCnt = (int*)carve(16);
    v2i* ovf = (v2i*)carve((size_t)OVF_CAP * 8);
    float4* h2 = (float4*)carve((size_t)N * 16);

    // uni region: binned pairs (msplit..fillp2) then aliased by h1 (gemm1..agg1).
    // cap adapts to ws_size; desired = mean + ~6 sigma.
    size_t h1_bytes = (size_t)N * DIM_HID * 4;
    int capDes = E / NB + E / NB / 16 + 256;
    size_t binned_des = (size_t)NB * capDes * 8;
    size_t uni_avail = (ws_size > off + 256) ? (ws_size - off - 256) : h1_bytes;
    size_t uni_bytes = binned_des > h1_bytes ? binned_des : h1_bytes;
    if (uni_bytes > uni_avail) uni_bytes = uni_avail > h1_bytes ? uni_avail : h1_bytes;
    char* uni = carve(uni_bytes);
    v2i* binned = (v2i*)uni;
    float* h1 = (float*)uni;
    int cap = (int)(uni_bytes / ((size_t)NB * 8));
    if (cap > capDes) cap = capDes;

    (void)hipMemsetAsync(cnt, 0, (size_t)N * 4, stream);
    (void)hipMemsetAsync(binCursor, 0, 128 * 4 + 256, stream);  // binCursor + ovfCnt
    k_detect<<<1, 64, 0, stream>>>(eidx, flag);

    k_msplit<<<MS_WGS, 256, 0, stream>>>(eidx, flag, cnt, binCursor, binned,
                                         ovfCnt, ovf, E, NB, cap);

    int NBLK = (N + 1023) / 1024;
    k_s1<<<NBLK, 1024, 0, stream>>>(cnt, dinv, bsum, N);
    k_s2<<<1, 64, 0, stream>>>(bsum, NBLK);
    k_s3<<<NBLK, 1024, 0, stream>>>(cnt, bsum, offsets, cursor, N);

    int bpx = (NB + 7) >> 3;
    k_fillp2<<<8 * bpx * GPB2, 256, 0, stream>>>(binned, binCursor, cursor, csr, cap, NB);
    k_ovf<<<1, 256, 0, stream>>>(ovfCnt, ovf, cursor, csr);

    k_gemm1<<<(N + 15) / 16, 256, 0, stream>>>(x, W1, h1, N);
    k_agg1<<<(N + 3) / 4, 256, 0, stream>>>(h1, csr, offsets, dinv, b1, W2, h2, N);
    k_agg2<<<(N + 3) / 4, 256, 0, stream>>>(h2, csr, offsets, dinv, b2, out, N);
}

// Round 6
// 346.221 us; speedup vs baseline: 2.1291x; 1.4547x over previous
//
#include <hip/hip_runtime.h>
#include <cstdint>
#include <cstddef>

#define DIM_IN 128
#define DIM_HID 64
#define MS_TILE 2048      // edges per multisplit tile
#define MS_WGS 1024       // msplit workgroups
#define OVF_CAP 32768     // overflow valve capacity (edges)

// native clang vectors (nontemporal builtins reject HIP_vector_type classes)
typedef int v2i __attribute__((ext_vector_type(2)));

// ---------- edge dtype detection: int32 (stride 1) vs int64 (stride 2) ----------
__global__ void k_detect(const int* __restrict__ e, int* __restrict__ flag) {
    if (blockIdx.x == 0 && threadIdx.x == 0) {
        int o = 0;
        for (int j = 1; j < 128; j += 2) o |= e[j];
        flag[0] = (o == 0) ? 2 : 1;
    }
}

// ---------- multisplit: eidx -> 98 dst-bins of packed (src<<10|ldst) words ----------
// No per-edge global atomics (R5 post-mortem: 3.2M device atomics = ~100MB of
// HBM write traffic). Only ~153k binCursor run-reservations remain.
__global__ __launch_bounds__(256) void k_msplit2(const int* __restrict__ eidx,
                                                 const int* __restrict__ flag,
                                                 int* __restrict__ binCursor,
                                                 unsigned int* __restrict__ binned,
                                                 int* __restrict__ ovfCnt,
                                                 v2i* __restrict__ ovf,
                                                 int E, int NB, int cap) {
    __shared__ int hist[128], base[128], scanb[128];
    __shared__ v2i buf[MS_TILE];  // {packed word, bin}
    int t = threadIdx.x;
    int st = flag[0];
    int ntiles = (E + MS_TILE - 1) / MS_TILE;

    for (int tile = blockIdx.x; tile < ntiles; tile += gridDim.x) {
        int e0 = tile * MS_TILE;
        int cntE = min(MS_TILE, E - e0);

        unsigned int words[8];
        int bins[8];
#pragma unroll
        for (int j = 0; j < 8; j++) {
            int e = e0 + t + 256 * j;
            if (e < E) {
                int s, d;
                if (st == 2) {
                    v2i a = __builtin_nontemporal_load((const v2i*)eidx + e);
                    v2i b = __builtin_nontemporal_load((const v2i*)eidx + E + e);
                    s = a.x; d = b.x;
                } else {
                    s = __builtin_nontemporal_load(&eidx[e]);
                    d = __builtin_nontemporal_load(&eidx[E + e]);
                }
                words[j] = ((unsigned int)s << 10) | (unsigned int)(d & 1023);
                bins[j] = d >> 10;
            } else {
                bins[j] = -1;
            }
        }

        if (t < 128) hist[t] = 0;
        __syncthreads();
#pragma unroll
        for (int j = 0; j < 8; j++)
            if (bins[j] >= 0) atomicAdd(&hist[bins[j]], 1);
        __syncthreads();
        if (t == 0) {               // tiny serial scan over <=128 bins
            int run = 0;
            for (int b = 0; b < NB; b++) { scanb[b] = run; run += hist[b]; }
        }
        __syncthreads();
        if (t < NB && hist[t] > 0) base[t] = atomicAdd(&binCursor[t], hist[t]);
        __syncthreads();
        if (t < 128) hist[t] = 0;   // reuse as rank counters
        __syncthreads();
#pragma unroll
        for (int j = 0; j < 8; j++) {
            if (bins[j] >= 0) {
                int r = atomicAdd(&hist[bins[j]], 1);
                buf[scanb[bins[j]] + r] = (v2i){(int)words[j], bins[j]};
            }
        }
        __syncthreads();
        for (int j = t; j < cntE; j += 256) {
            v2i p = buf[j];
            int b = p.y;
            int local = base[b] + (j - scanb[b]);
            if (local < cap) {
                binned[(size_t)b * cap + local] = (unsigned int)p.x;
            } else {
                int o = atomicAdd(ovfCnt, 1);
                if (o < OVF_CAP)
                    ovf[o] = (v2i){(int)((unsigned int)p.x >> 10),
                                   (b << 10) | (p.x & 1023)};
            }
        }
        __syncthreads();
    }
}

// ---------- per-bin degree histogram in LDS (no global atomics) ----------
__global__ __launch_bounds__(1024) void k_binhist(const unsigned int* __restrict__ binned,
                                                  const int* __restrict__ binCursor,
                                                  int* __restrict__ cnt,
                                                  int cap, int N) {
    __shared__ int hist[1024];
    int b = blockIdx.x;
    int t = threadIdx.x;
    hist[t] = 0;
    __syncthreads();
    int n = min(binCursor[b], cap);
    const unsigned int* p = binned + (size_t)b * cap;
    for (int i = t; i < n; i += 1024) {
        unsigned int w = __builtin_nontemporal_load(p + i);
        atomicAdd(&hist[w & 1023], 1);
    }
    __syncthreads();
    int g = b * 1024 + t;
    if (g < N) cnt[g] = hist[t];
}

// ---------- scan S1: per-1024-chunk sums; also dinv = rsqrt(cnt+1) ----------
__global__ __launch_bounds__(1024) void k_s1(const int* __restrict__ cnt,
                                             float* __restrict__ dinv,
                                             int* __restrict__ bsum, int N) {
    __shared__ int sh[1024];
    int t = threadIdx.x;
    int i = blockIdx.x * 1024 + t;
    int c = (i < N) ? cnt[i] : 0;
    if (i < N) dinv[i] = rsqrtf((float)(c + 1));
    sh[t] = c;
    __syncthreads();
    for (int d = 512; d > 0; d >>= 1) {
        if (t < d) sh[t] += sh[t + d];
        __syncthreads();
    }
    if (t == 0) bsum[blockIdx.x] = sh[0];
}

__global__ void k_s2(int* __restrict__ bsum, int NB) {
    if (blockIdx.x == 0 && threadIdx.x == 0) {
        int run = 0;
        for (int b = 0; b < NB; b++) { int v = bsum[b]; bsum[b] = run; run += v; }
    }
}

__global__ __launch_bounds__(1024) void k_s3(const int* __restrict__ cnt,
                                             const int* __restrict__ bsum,
                                             int* __restrict__ offsets,
                                             int* __restrict__ cursor, int N) {
    __shared__ int sh[1024];
    int t = threadIdx.x;
    int i = blockIdx.x * 1024 + t;
    int c = (i < N) ? cnt[i] : 0;
    sh[t] = c;
    __syncthreads();
    for (int d = 1; d < 1024; d <<= 1) {
        int add = (t >= d) ? sh[t - d] : 0;
        __syncthreads();
        sh[t] += add;
        __syncthreads();
    }
    if (i < N) {
        int incl = bsum[blockIdx.x] + sh[t];
        offsets[i + 1] = incl;
        cursor[i] = incl - c;
    }
    if (i == 0) offsets[0] = 0;
}

// ---------- CSR fill: one WG per bin, cursor slice in LDS ----------
// LDS atomics for placement; csr writes confined to this bin's ~131KB window
// on one CU -> its XCD L2 absorbs them; zero global atomics on the hot path.
__global__ __launch_bounds__(1024) void k_fill3(const unsigned int* __restrict__ binned,
                                                const int* __restrict__ binCursor,
                                                int* __restrict__ cursor,
                                                int* __restrict__ csr,
                                                int cap, int N) {
    __shared__ int cur[1024];
    int b = blockIdx.x;
    int t = threadIdx.x;
    int g = b * 1024 + t;
    if (g < N) cur[t] = cursor[g];
    __syncthreads();
    int n = min(binCursor[b], cap);
    const unsigned int* p = binned + (size_t)b * cap;
    for (int i = t; i < n; i += 1024) {
        unsigned int w = __builtin_nontemporal_load(p + i);
        int pos = atomicAdd(&cur[w & 1023], 1);
        csr[pos] = (int)(w >> 10);
    }
    __syncthreads();
    if (g < N) cursor[g] = cur[t];   // final positions, for the overflow valve
}

// ---------- drain overflow valve (normally 0 edges) ----------
__global__ void k_ovf(const int* __restrict__ ovfCnt, const v2i* __restrict__ ovf,
                      int* __restrict__ cursor, int* __restrict__ csr) {
    int n = min(*ovfCnt, OVF_CAP);
    for (int i = threadIdx.x; i < n; i += 256) {
        v2i e = ovf[i];
        int pos = atomicAdd(&cursor[e.y], 1);
        csr[pos] = e.x;
    }
}

// ---------- GEMM1: h1 = x @ W1, [N,128]x[128,64] fp32 ----------
__global__ __launch_bounds__(256) void k_gemm1(const float* __restrict__ x,
                                               const float* __restrict__ W,
                                               float* __restrict__ h1, int N) {
    __shared__ float Ws[DIM_IN * DIM_HID];
    int t = threadIdx.x;
#pragma unroll
    for (int i = 0; i < 8; i++)
        ((float4*)Ws)[t + 256 * i] = ((const float4*)W)[t + 256 * i];
    __syncthreads();

    int col = t & 63;
    int rg = __builtin_amdgcn_readfirstlane(t >> 6);
    int row0 = blockIdx.x * 16 + rg * 4;
    if (row0 >= N) return;

    const float* xr = x + (size_t)row0 * DIM_IN;
    float a0 = 0.f, a1 = 0.f, a2 = 0.f, a3 = 0.f;
#pragma unroll 4
    for (int k = 0; k < DIM_IN; k++) {
        float w = Ws[k * DIM_HID + col];
        a0 = fmaf(xr[k], w, a0);
        a1 = fmaf(xr[DIM_IN + k], w, a1);
        a2 = fmaf(xr[2 * DIM_IN + k], w, a2);
        a3 = fmaf(xr[3 * DIM_IN + k], w, a3);
    }
    size_t o = (size_t)row0 * DIM_HID + col;
    h1[o] = a0;
    h1[o + DIM_HID] = a1;
    h1[o + 2 * DIM_HID] = a2;
    h1[o + 3 * DIM_HID] = a3;
}

// ---------- agg1 fused: g = relu(A_norm h1 + b1); h2 = g @ W2 ----------
__global__ __launch_bounds__(256) void k_agg1(const float* __restrict__ h1,
                                              const int* __restrict__ csr,
                                              const int* __restrict__ offsets,
                                              const float* __restrict__ dinv,
                                              const float* __restrict__ b1,
                                              const float* __restrict__ W2,
                                              float4* __restrict__ h2, int N) {
    int t = threadIdx.x;
    int lane = t & 63;
    int node = blockIdx.x * 4 + (t >> 6);
    if (node >= N) return;

    float di = dinv[node];
    int beg = offsets[node], end = offsets[node + 1];
    float acc = h1[(size_t)node * 64 + lane] * di * di;  // self-loop

    int e = beg;
    for (; e + 3 < end; e += 4) {
        int s0 = csr[e], s1 = csr[e + 1], s2 = csr[e + 2], s3 = csr[e + 3];
        float w0 = dinv[s0] * di, w1 = dinv[s1] * di;
        float w2 = dinv[s2] * di, w3 = dinv[s3] * di;
        acc = fmaf(h1[(size_t)s0 * 64 + lane], w0, acc);
        acc = fmaf(h1[(size_t)s1 * 64 + lane], w1, acc);
        acc = fmaf(h1[(size_t)s2 * 64 + lane], w2, acc);
        acc = fmaf(h1[(size_t)s3 * 64 + lane], w3, acc);
    }
    for (; e < end; e++) {
        int s0 = csr[e];
        acc = fmaf(h1[(size_t)s0 * 64 + lane], dinv[s0] * di, acc);
    }

    float g = fmaxf(acc + b1[lane], 0.f);

    float v0 = g * W2[lane * 3 + 0];
    float v1 = g * W2[lane * 3 + 1];
    float v2 = g * W2[lane * 3 + 2];
#pragma unroll
    for (int off = 32; off > 0; off >>= 1) {
        v0 += __shfl_xor(v0, off, 64);
        v1 += __shfl_xor(v1, off, 64);
        v2 += __shfl_xor(v2, off, 64);
    }
    if (lane == 0) h2[node] = make_float4(v0, v1, v2, 0.f);
}

// ---------- agg2: out = A_norm h2 + b2, [N,3] ----------
__global__ __launch_bounds__(256) void k_agg2(const float4* __restrict__ h2,
                                              const int* __restrict__ csr,
                                              const int* __restrict__ offsets,
                                              const float* __restrict__ dinv,
                                              const float* __restrict__ b2,
                                              float* __restrict__ out, int N) {
    int t = threadIdx.x;
    int lane = t & 63;
    int node = blockIdx.x * 4 + (t >> 6);
    if (node >= N) return;

    float di = dinv[node];
    int beg = offsets[node], end = offsets[node + 1];
    float a0 = 0.f, a1 = 0.f, a2 = 0.f;
    for (int e = beg + lane; e < end; e += 64) {
        int s = csr[e];
        float w = dinv[s] * di;
        float4 h = h2[s];
        a0 = fmaf(h.x, w, a0);
        a1 = fmaf(h.y, w, a1);
        a2 = fmaf(h.z, w, a2);
    }
#pragma unroll
    for (int off = 32; off > 0; off >>= 1) {
        a0 += __shfl_xor(a0, off, 64);
        a1 += __shfl_xor(a1, off, 64);
        a2 += __shfl_xor(a2, off, 64);
    }
    if (lane == 0) {
        float4 hs = h2[node];
        float sl = di * di;
        out[(size_t)node * 3 + 0] = a0 + hs.x * sl + b2[0];
        out[(size_t)node * 3 + 1] = a1 + hs.y * sl + b2[1];
        out[(size_t)node * 3 + 2] = a2 + hs.z * sl + b2[2];
    }
}

extern "C" void kernel_launch(void* const* d_in, const int* in_sizes, int n_in,
                              void* d_out, int out_size, void* d_ws, size_t ws_size,
                              hipStream_t stream) {
    const float* x = (const float*)d_in[0];
    const int* eidx = (const int*)d_in[1];
    const float* W1 = (const float*)d_in[2];
    const float* b1 = (const float*)d_in[3];
    const float* W2 = (const float*)d_in[4];
    const float* b2 = (const float*)d_in[5];
    float* out = (float*)d_out;

    const int N = in_sizes[0] / DIM_IN;   // 100000
    const int E = in_sizes[1] / 2;        // 3200000
    const int NB = (N + 1023) >> 10;      // dst bins of 1024 nodes (<=128)

    char* w = (char*)d_ws;
    size_t off = 0;
    auto carve = [&](size_t bytes) -> char* {
        char* p = w + off;
        off += (bytes + 255) & ~(size_t)255;
        return p;
    };
    int* flag = (int*)carve(16);
    int* cnt = (int*)carve((size_t)N * 4);
    int* offsets = (int*)carve((size_t)(N + 1) * 4);
    int* cursor = (int*)carve((size_t)N * 4);
    int* bsum = (int*)carve(1024 * 4);
    float* dinv = (float*)carve((size_t)N * 4);
    int* csr = (int*)carve((size_t)E * 4);
    int* binCursor = (int*)carve(128 * 4);
    int* ovfCnt = (int*)carve(16);
    v2i* ovf = (v2i*)carve((size_t)OVF_CAP * 8);
    float4* h2 = (float4*)carve((size_t)N * 16);

    // uni region: packed binned words (msplit..fill3) then aliased by h1.
    size_t h1_bytes = (size_t)N * DIM_HID * 4;
    int capDes = E / NB + E / NB / 16 + 256;     // mean + ~12 sigma
    size_t binned_des = (size_t)NB * capDes * 4;
    size_t uni_avail = (ws_size > off + 256) ? (ws_size - off - 256) : h1_bytes;
    size_t uni_bytes = binned_des > h1_bytes ? binned_des : h1_bytes;
    if (uni_bytes > uni_avail) uni_bytes = uni_avail > h1_bytes ? uni_avail : h1_bytes;
    char* uni = carve(uni_bytes);
    unsigned int* binned = (unsigned int*)uni;
    float* h1 = (float*)uni;
    int cap = (int)(uni_bytes / ((size_t)NB * 4));
    if (cap > capDes) cap = capDes;

    (void)hipMemsetAsync(binCursor, 0, 128 * 4 + 256, stream);  // binCursor + ovfCnt
    k_detect<<<1, 64, 0, stream>>>(eidx, flag);

    k_msplit2<<<MS_WGS, 256, 0, stream>>>(eidx, flag, binCursor, binned,
                                          ovfCnt, ovf, E, NB, cap);
    k_binhist<<<NB, 1024, 0, stream>>>(binned, binCursor, cnt, cap, N);

    int NBLK = (N + 1023) / 1024;
    k_s1<<<NBLK, 1024, 0, stream>>>(cnt, dinv, bsum, N);
    k_s2<<<1, 64, 0, stream>>>(bsum, NBLK);
    k_s3<<<NBLK, 1024, 0, stream>>>(cnt, bsum, offsets, cursor, N);

    k_fill3<<<NB, 1024, 0, stream>>>(binned, binCursor, cursor, csr, cap, N);
    k_ovf<<<1, 256, 0, stream>>>(ovfCnt, ovf, cursor, csr);

    k_gemm1<<<(N + 15) / 16, 256, 0, stream>>>(x, W1, h1, N);
    k_agg1<<<(N + 3) / 4, 256, 0, stream>>>(h1, csr, offsets, dinv, b1, W2, h2, N);
    k_agg2<<<(N + 3) / 4, 256, 0, stream>>>(h2, csr, offsets, dinv, b2, out, N);
}

// Round 7
// 296.594 us; speedup vs baseline: 2.4854x; 1.1673x over previous
//
#include <hip/hip_runtime.h>
#include <hip/hip_fp16.h>
#include <cstdint>
#include <cstddef>

#define DIM_IN 128
#define DIM_HID 64
#define MS_TILE 2048      // edges per multisplit tile
#define MS_WGS 1024       // msplit workgroups
#define OVF_CAP 32768     // overflow valve capacity (edges)

// native clang vectors (nontemporal builtins reject HIP_vector_type classes)
typedef int v2i __attribute__((ext_vector_type(2)));

// ---------- edge dtype detection: int32 (stride 1) vs int64 (stride 2) ----------
__global__ void k_detect(const int* __restrict__ e, int* __restrict__ flag) {
    if (blockIdx.x == 0 && threadIdx.x == 0) {
        int o = 0;
        for (int j = 1; j < 128; j += 2) o |= e[j];
        flag[0] = (o == 0) ? 2 : 1;
    }
}

// ---------- multisplit: eidx -> dst-bins of packed (src<<10|ldst) words ----------
// No per-edge global atomics (R5 post-mortem: 3.2M device atomics = ~100MB of
// HBM write traffic). Only ~153k binCursor run-reservations remain.
__global__ __launch_bounds__(256) void k_msplit2(const int* __restrict__ eidx,
                                                 const int* __restrict__ flag,
                                                 int* __restrict__ binCursor,
                                                 unsigned int* __restrict__ binned,
                                                 int* __restrict__ ovfCnt,
                                                 v2i* __restrict__ ovf,
                                                 int E, int NB, int cap) {
    __shared__ int hist[128], base[128], scanb[128];
    __shared__ v2i buf[MS_TILE];  // {packed word, bin}
    int t = threadIdx.x;
    int st = flag[0];
    int ntiles = (E + MS_TILE - 1) / MS_TILE;

    for (int tile = blockIdx.x; tile < ntiles; tile += gridDim.x) {
        int e0 = tile * MS_TILE;
        int cntE = min(MS_TILE, E - e0);

        unsigned int words[8];
        int bins[8];
#pragma unroll
        for (int j = 0; j < 8; j++) {
            int e = e0 + t + 256 * j;
            if (e < E) {
                int s, d;
                if (st == 2) {
                    v2i a = __builtin_nontemporal_load((const v2i*)eidx + e);
                    v2i b = __builtin_nontemporal_load((const v2i*)eidx + E + e);
                    s = a.x; d = b.x;
                } else {
                    s = __builtin_nontemporal_load(&eidx[e]);
                    d = __builtin_nontemporal_load(&eidx[E + e]);
                }
                words[j] = ((unsigned int)s << 10) | (unsigned int)(d & 1023);
                bins[j] = d >> 10;
            } else {
                bins[j] = -1;
            }
        }

        if (t < 128) hist[t] = 0;
        __syncthreads();
#pragma unroll
        for (int j = 0; j < 8; j++)
            if (bins[j] >= 0) atomicAdd(&hist[bins[j]], 1);
        __syncthreads();
        if (t == 0) {               // tiny serial scan over <=128 bins
            int run = 0;
            for (int b = 0; b < NB; b++) { scanb[b] = run; run += hist[b]; }
        }
        __syncthreads();
        if (t < NB && hist[t] > 0) base[t] = atomicAdd(&binCursor[t], hist[t]);
        __syncthreads();
        if (t < 128) hist[t] = 0;   // reuse as rank counters
        __syncthreads();
#pragma unroll
        for (int j = 0; j < 8; j++) {
            if (bins[j] >= 0) {
                int r = atomicAdd(&hist[bins[j]], 1);
                buf[scanb[bins[j]] + r] = (v2i){(int)words[j], bins[j]};
            }
        }
        __syncthreads();
        for (int j = t; j < cntE; j += 256) {
            v2i p = buf[j];
            int b = p.y;
            int local = base[b] + (j - scanb[b]);
            if (local < cap) {
                binned[(size_t)b * cap + local] = (unsigned int)p.x;
            } else {
                int o = atomicAdd(ovfCnt, 1);
                if (o < OVF_CAP)
                    ovf[o] = (v2i){(int)((unsigned int)p.x >> 10),
                                   (b << 10) | (p.x & 1023)};
            }
        }
        __syncthreads();
    }
}

// ---------- per-bin degree histogram in LDS (no global atomics) ----------
__global__ __launch_bounds__(1024) void k_binhist(const unsigned int* __restrict__ binned,
                                                  const int* __restrict__ binCursor,
                                                  int* __restrict__ cnt,
                                                  int cap, int N) {
    __shared__ int hist[1024];
    int b = blockIdx.x;
    int t = threadIdx.x;
    hist[t] = 0;
    __syncthreads();
    int n = min(binCursor[b], cap);
    const unsigned int* p = binned + (size_t)b * cap;
    for (int i = t; i < n; i += 1024) {
        unsigned int w = __builtin_nontemporal_load(p + i);
        atomicAdd(&hist[w & 1023], 1);
    }
    __syncthreads();
    int g = b * 1024 + t;
    if (g < N) cnt[g] = hist[t];
}

// ---------- scan S1: per-1024-chunk sums; also dinv = rsqrt(cnt+1) ----------
__global__ __launch_bounds__(1024) void k_s1(const int* __restrict__ cnt,
                                             float* __restrict__ dinv,
                                             int* __restrict__ bsum, int N) {
    __shared__ int sh[1024];
    int t = threadIdx.x;
    int i = blockIdx.x * 1024 + t;
    int c = (i < N) ? cnt[i] : 0;
    if (i < N) dinv[i] = rsqrtf((float)(c + 1));
    sh[t] = c;
    __syncthreads();
    for (int d = 512; d > 0; d >>= 1) {
        if (t < d) sh[t] += sh[t + d];
        __syncthreads();
    }
    if (t == 0) bsum[blockIdx.x] = sh[0];
}

__global__ void k_s2(int* __restrict__ bsum, int NB) {
    if (blockIdx.x == 0 && threadIdx.x == 0) {
        int run = 0;
        for (int b = 0; b < NB; b++) { int v = bsum[b]; bsum[b] = run; run += v; }
    }
}

__global__ __launch_bounds__(1024) void k_s3(const int* __restrict__ cnt,
                                             const int* __restrict__ bsum,
                                             int* __restrict__ offsets,
                                             int* __restrict__ cursor, int N) {
    __shared__ int sh[1024];
    int t = threadIdx.x;
    int i = blockIdx.x * 1024 + t;
    int c = (i < N) ? cnt[i] : 0;
    sh[t] = c;
    __syncthreads();
    for (int d = 1; d < 1024; d <<= 1) {
        int add = (t >= d) ? sh[t - d] : 0;
        __syncthreads();
        sh[t] += add;
        __syncthreads();
    }
    if (i < N) {
        int incl = bsum[blockIdx.x] + sh[t];
        offsets[i + 1] = incl;
        cursor[i] = incl - c;
    }
    if (i == 0) offsets[0] = 0;
}

// ---------- CSR fill: one WG per bin, cursor slice in LDS ----------
__global__ __launch_bounds__(1024) void k_fill3(const unsigned int* __restrict__ binned,
                                                const int* __restrict__ binCursor,
                                                int* __restrict__ cursor,
                                                int* __restrict__ csr,
                                                int cap, int N) {
    __shared__ int cur[1024];
    int b = blockIdx.x;
    int t = threadIdx.x;
    int g = b * 1024 + t;
    if (g < N) cur[t] = cursor[g];
    __syncthreads();
    int n = min(binCursor[b], cap);
    const unsigned int* p = binned + (size_t)b * cap;
    for (int i = t; i < n; i += 1024) {
        unsigned int w = __builtin_nontemporal_load(p + i);
        int pos = atomicAdd(&cur[w & 1023], 1);
        csr[pos] = (int)(w >> 10);
    }
    __syncthreads();
    if (g < N) cursor[g] = cur[t];   // final positions, for the overflow valve
}

// ---------- drain overflow valve (normally 0 edges) ----------
__global__ void k_ovf(const int* __restrict__ ovfCnt, const v2i* __restrict__ ovf,
                      int* __restrict__ cursor, int* __restrict__ csr) {
    int n = min(*ovfCnt, OVF_CAP);
    for (int i = threadIdx.x; i < n; i += 256) {
        v2i e = ovf[i];
        int pos = atomicAdd(&cursor[e.y], 1);
        csr[pos] = e.x;
    }
}

// ---------- GEMM1: h1' = (x @ W1) * dinv[row], fp16-packed [N,32] u32 ----------
// dinv folded in so agg1 needs no per-edge dinv gather or weight fma.
// Thread = 2 cols x 2 rows; fp16 pair (cols 2c,2c+1) packs to one u32 store.
__global__ __launch_bounds__(256) void k_gemm1(const float* __restrict__ x,
                                               const float* __restrict__ W,
                                               const float* __restrict__ dinv,
                                               __half2* __restrict__ h1, int N) {
    __shared__ float Ws[DIM_IN * DIM_HID];
    int t = threadIdx.x;
#pragma unroll
    for (int i = 0; i < 8; i++)
        ((float4*)Ws)[t + 256 * i] = ((const float4*)W)[t + 256 * i];
    __syncthreads();

    int c = t & 31;                 // col pair -> cols 2c, 2c+1
    int rp = t >> 5;                // row pair 0..7
    int row0 = blockIdx.x * 16 + rp * 2;
    if (row0 >= N) return;

    const float* xr = x + (size_t)row0 * DIM_IN;
    float a00 = 0.f, a01 = 0.f, a10 = 0.f, a11 = 0.f;
#pragma unroll 4
    for (int k = 0; k < DIM_IN; k++) {
        float2 w = ((const float2*)(Ws + k * DIM_HID))[c];
        float x0 = xr[k], x1 = xr[DIM_IN + k];
        a00 = fmaf(x0, w.x, a00);
        a01 = fmaf(x0, w.y, a01);
        a10 = fmaf(x1, w.x, a10);
        a11 = fmaf(x1, w.y, a11);
    }
    float d0 = dinv[row0];
    float d1 = (row0 + 1 < N) ? dinv[row0 + 1] : 0.f;
    h1[(size_t)row0 * 32 + c] = __floats2half2_rn(a00 * d0, a01 * d0);
    if (row0 + 1 < N)
        h1[(size_t)(row0 + 1) * 32 + c] = __floats2half2_rn(a10 * d1, a11 * d1);
}

// ---------- agg1: g = relu(di*(sum h1'[src] + h1'[node]) + b1); h2' = (g@W2)*di ----------
// Half-wave per node: 32 lanes x u32(__half2) = one 128B row per gather.
__global__ __launch_bounds__(256) void k_agg1(const __half2* __restrict__ h1,
                                              const int* __restrict__ csr,
                                              const int* __restrict__ offsets,
                                              const float* __restrict__ dinv,
                                              const float* __restrict__ b1,
                                              const float* __restrict__ W2,
                                              float4* __restrict__ h2, int N) {
    int t = threadIdx.x;
    int hl = t & 31;
    int node = blockIdx.x * 8 + (t >> 5);
    if (node >= N) return;

    float di = dinv[node];
    int beg = offsets[node], end = offsets[node + 1];
    float2 acc = __half22float2(h1[(size_t)node * 32 + hl]);  // self-loop (pre-scaled)

    int e = beg;
    for (; e + 3 < end; e += 4) {
        int s0 = csr[e], s1 = csr[e + 1], s2 = csr[e + 2], s3 = csr[e + 3];
        float2 f0 = __half22float2(h1[(size_t)s0 * 32 + hl]);
        float2 f1 = __half22float2(h1[(size_t)s1 * 32 + hl]);
        float2 f2 = __half22float2(h1[(size_t)s2 * 32 + hl]);
        float2 f3 = __half22float2(h1[(size_t)s3 * 32 + hl]);
        acc.x += (f0.x + f1.x) + (f2.x + f3.x);
        acc.y += (f0.y + f1.y) + (f2.y + f3.y);
    }
    for (; e < end; e++) {
        float2 f = __half22float2(h1[(size_t)csr[e] * 32 + hl]);
        acc.x += f.x;
        acc.y += f.y;
    }

    float2 bb = ((const float2*)b1)[hl];
    float gx = fmaxf(fmaf(acc.x, di, bb.x), 0.f);
    float gy = fmaxf(fmaf(acc.y, di, bb.y), 0.f);

    const float* w0 = W2 + (2 * hl) * 3;
    const float* w1 = W2 + (2 * hl + 1) * 3;
    float v0 = gx * w0[0] + gy * w1[0];
    float v1 = gx * w0[1] + gy * w1[1];
    float v2 = gx * w0[2] + gy * w1[2];
#pragma unroll
    for (int off = 16; off > 0; off >>= 1) {
        v0 += __shfl_xor(v0, off, 64);
        v1 += __shfl_xor(v1, off, 64);
        v2 += __shfl_xor(v2, off, 64);
    }
    if (hl == 0) h2[node] = make_float4(v0 * di, v1 * di, v2 * di, 0.f);
}

// ---------- agg2: out = di*(sum h2'[src] + h2'[node]) + b2 ----------
__global__ __launch_bounds__(256) void k_agg2(const float4* __restrict__ h2,
                                              const int* __restrict__ csr,
                                              const int* __restrict__ offsets,
                                              const float* __restrict__ dinv,
                                              const float* __restrict__ b2,
                                              float* __restrict__ out, int N) {
    int t = threadIdx.x;
    int lane = t & 63;
    int node = blockIdx.x * 4 + (t >> 6);
    if (node >= N) return;

    float di = dinv[node];
    int beg = offsets[node], end = offsets[node + 1];
    float a0 = 0.f, a1 = 0.f, a2 = 0.f;
    for (int e = beg + lane; e < end; e += 64) {
        float4 h = h2[csr[e]];
        a0 += h.x;
        a1 += h.y;
        a2 += h.z;
    }
#pragma unroll
    for (int off = 32; off > 0; off >>= 1) {
        a0 += __shfl_xor(a0, off, 64);
        a1 += __shfl_xor(a1, off, 64);
        a2 += __shfl_xor(a2, off, 64);
    }
    if (lane == 0) {
        float4 hs = h2[node];
        out[(size_t)node * 3 + 0] = fmaf(a0 + hs.x, di, b2[0]);
        out[(size_t)node * 3 + 1] = fmaf(a1 + hs.y, di, b2[1]);
        out[(size_t)node * 3 + 2] = fmaf(a2 + hs.z, di, b2[2]);
    }
}

extern "C" void kernel_launch(void* const* d_in, const int* in_sizes, int n_in,
                              void* d_out, int out_size, void* d_ws, size_t ws_size,
                              hipStream_t stream) {
    const float* x = (const float*)d_in[0];
    const int* eidx = (const int*)d_in[1];
    const float* W1 = (const float*)d_in[2];
    const float* b1 = (const float*)d_in[3];
    const float* W2 = (const float*)d_in[4];
    const float* b2 = (const float*)d_in[5];
    float* out = (float*)d_out;

    const int N = in_sizes[0] / DIM_IN;   // 100000
    const int E = in_sizes[1] / 2;        // 3200000
    const int NB = (N + 1023) >> 10;      // dst bins of 1024 nodes (<=128)

    char* w = (char*)d_ws;
    size_t off = 0;
    auto carve = [&](size_t bytes) -> char* {
        char* p = w + off;
        off += (bytes + 255) & ~(size_t)255;
        return p;
    };
    int* flag = (int*)carve(16);
    int* cnt = (int*)carve((size_t)N * 4);
    int* offsets = (int*)carve((size_t)(N + 1) * 4);
    int* cursor = (int*)carve((size_t)N * 4);
    int* bsum = (int*)carve(1024 * 4);
    float* dinv = (float*)carve((size_t)N * 4);
    int* csr = (int*)carve((size_t)E * 4);
    int* binCursor = (int*)carve(128 * 4);
    int* ovfCnt = (int*)carve(16);
    v2i* ovf = (v2i*)carve((size_t)OVF_CAP * 8);
    float4* h2 = (float4*)carve((size_t)N * 16);

    // uni region: packed binned words (msplit..fill3), then aliased by fp16 h1'.
    size_t h1_bytes = (size_t)N * DIM_HID * 2;
    int capDes = E / NB + E / NB / 16 + 256;     // mean + margin
    size_t binned_des = (size_t)NB * capDes * 4;
    size_t uni_avail = (ws_size > off + 256) ? (ws_size - off - 256) : h1_bytes;
    size_t uni_bytes = binned_des > h1_bytes ? binned_des : h1_bytes;
    if (uni_bytes > uni_avail) uni_bytes = uni_avail > h1_bytes ? uni_avail : h1_bytes;
    char* uni = carve(uni_bytes);
    unsigned int* binned = (unsigned int*)uni;
    __half2* h1 = (__half2*)uni;        // aliased: valid only after k_fill3
    int cap = (int)(uni_bytes / ((size_t)NB * 4));
    if (cap > capDes) cap = capDes;

    (void)hipMemsetAsync(binCursor, 0, 128 * 4 + 256, stream);  // binCursor + ovfCnt
    k_detect<<<1, 64, 0, stream>>>(eidx, flag);

    k_msplit2<<<MS_WGS, 256, 0, stream>>>(eidx, flag, binCursor, binned,
                                          ovfCnt, ovf, E, NB, cap);
    k_binhist<<<NB, 1024, 0, stream>>>(binned, binCursor, cnt, cap, N);

    int NBLK = (N + 1023) / 1024;
    k_s1<<<NBLK, 1024, 0, stream>>>(cnt, dinv, bsum, N);
    k_s2<<<1, 64, 0, stream>>>(bsum, NBLK);
    k_s3<<<NBLK, 1024, 0, stream>>>(cnt, bsum, offsets, cursor, N);

    k_fill3<<<NB, 1024, 0, stream>>>(binned, binCursor, cursor, csr, cap, N);
    k_ovf<<<1, 256, 0, stream>>>(ovfCnt, ovf, cursor, csr);

    k_gemm1<<<(N + 15) / 16, 256, 0, stream>>>(x, W1, dinv, h1, N);
    k_agg1<<<(N + 7) / 8, 256, 0, stream>>>(h1, csr, offsets, dinv, b1, W2, h2, N);
    k_agg2<<<(N + 3) / 4, 256, 0, stream>>>(h2, csr, offsets, dinv, b2, out, N);
}

// Round 8
// 269.795 us; speedup vs baseline: 2.7323x; 1.0993x over previous
//
#include <hip/hip_runtime.h>
#include <hip/hip_fp16.h>
#include <cstdint>
#include <cstddef>

#define DIM_IN 128
#define DIM_HID 64
#define MS_TILE 2048      // edges per multisplit tile
#define MS_WGS 1024       // msplit workgroups
#define OVF_CAP 32768     // overflow valve capacity (edges)

// native clang vectors (nontemporal builtins reject HIP_vector_type classes)
typedef int v2i __attribute__((ext_vector_type(2)));

// ---------- edge dtype detection: int32 (stride 1) vs int64 (stride 2) ----------
__global__ void k_detect(const int* __restrict__ e, int* __restrict__ flag) {
    if (blockIdx.x == 0 && threadIdx.x == 0) {
        int o = 0;
        for (int j = 1; j < 128; j += 2) o |= e[j];
        flag[0] = (o == 0) ? 2 : 1;
    }
}

// ---------- multisplit: eidx -> dst-bins of packed (src<<10|ldst) words ----------
__global__ __launch_bounds__(256) void k_msplit2(const int* __restrict__ eidx,
                                                 const int* __restrict__ flag,
                                                 int* __restrict__ binCursor,
                                                 unsigned int* __restrict__ binned,
                                                 int* __restrict__ ovfCnt,
                                                 v2i* __restrict__ ovf,
                                                 int E, int NB, int cap) {
    __shared__ int hist[128], base[128], scanb[128];
    __shared__ v2i buf[MS_TILE];  // {packed word, bin}
    int t = threadIdx.x;
    int st = flag[0];
    int ntiles = (E + MS_TILE - 1) / MS_TILE;

    for (int tile = blockIdx.x; tile < ntiles; tile += gridDim.x) {
        int e0 = tile * MS_TILE;
        int cntE = min(MS_TILE, E - e0);

        unsigned int words[8];
        int bins[8];
#pragma unroll
        for (int j = 0; j < 8; j++) {
            int e = e0 + t + 256 * j;
            if (e < E) {
                int s, d;
                if (st == 2) {
                    v2i a = __builtin_nontemporal_load((const v2i*)eidx + e);
                    v2i b = __builtin_nontemporal_load((const v2i*)eidx + E + e);
                    s = a.x; d = b.x;
                } else {
                    s = __builtin_nontemporal_load(&eidx[e]);
                    d = __builtin_nontemporal_load(&eidx[E + e]);
                }
                words[j] = ((unsigned int)s << 10) | (unsigned int)(d & 1023);
                bins[j] = d >> 10;
            } else {
                bins[j] = -1;
            }
        }

        if (t < 128) hist[t] = 0;
        __syncthreads();
#pragma unroll
        for (int j = 0; j < 8; j++)
            if (bins[j] >= 0) atomicAdd(&hist[bins[j]], 1);
        __syncthreads();
        if (t == 0) {               // tiny serial scan over <=128 bins
            int run = 0;
            for (int b = 0; b < NB; b++) { scanb[b] = run; run += hist[b]; }
        }
        __syncthreads();
        if (t < NB && hist[t] > 0) base[t] = atomicAdd(&binCursor[t], hist[t]);
        __syncthreads();
        if (t < 128) hist[t] = 0;   // reuse as rank counters
        __syncthreads();
#pragma unroll
        for (int j = 0; j < 8; j++) {
            if (bins[j] >= 0) {
                int r = atomicAdd(&hist[bins[j]], 1);
                buf[scanb[bins[j]] + r] = (v2i){(int)words[j], bins[j]};
            }
        }
        __syncthreads();
        for (int j = t; j < cntE; j += 256) {
            v2i p = buf[j];
            int b = p.y;
            int local = base[b] + (j - scanb[b]);
            if (local < cap) {
                binned[(size_t)b * cap + local] = (unsigned int)p.x;
            } else {
                int o = atomicAdd(ovfCnt, 1);
                if (o < OVF_CAP)
                    ovf[o] = (v2i){(int)((unsigned int)p.x >> 10),
                                   (b << 10) | (p.x & 1023)};
            }
        }
        __syncthreads();
    }
}

// ---------- per-bin degree histogram in LDS (no global atomics) ----------
__global__ __launch_bounds__(1024) void k_binhist(const unsigned int* __restrict__ binned,
                                                  const int* __restrict__ binCursor,
                                                  int* __restrict__ cnt,
                                                  int cap, int N) {
    __shared__ int hist[1024];
    int b = blockIdx.x;
    int t = threadIdx.x;
    hist[t] = 0;
    __syncthreads();
    int n = min(binCursor[b], cap);
    const unsigned int* p = binned + (size_t)b * cap;
    for (int i = t; i < n; i += 1024) {
        unsigned int w = __builtin_nontemporal_load(p + i);
        atomicAdd(&hist[w & 1023], 1);
    }
    __syncthreads();
    int g = b * 1024 + t;
    if (g < N) cnt[g] = hist[t];
}

// ---------- scan S1: per-1024-chunk sums; also dinv = rsqrt(cnt+1) ----------
__global__ __launch_bounds__(1024) void k_s1(const int* __restrict__ cnt,
                                             float* __restrict__ dinv,
                                             int* __restrict__ bsum, int N) {
    __shared__ int sh[1024];
    int t = threadIdx.x;
    int i = blockIdx.x * 1024 + t;
    int c = (i < N) ? cnt[i] : 0;
    if (i < N) dinv[i] = rsqrtf((float)(c + 1));
    sh[t] = c;
    __syncthreads();
    for (int d = 512; d > 0; d >>= 1) {
        if (t < d) sh[t] += sh[t + d];
        __syncthreads();
    }
    if (t == 0) bsum[blockIdx.x] = sh[0];
}

__global__ void k_s2(int* __restrict__ bsum, int NB) {
    if (blockIdx.x == 0 && threadIdx.x == 0) {
        int run = 0;
        for (int b = 0; b < NB; b++) { int v = bsum[b]; bsum[b] = run; run += v; }
    }
}

__global__ __launch_bounds__(1024) void k_s3(const int* __restrict__ cnt,
                                             const int* __restrict__ bsum,
                                             int* __restrict__ offsets,
                                             int* __restrict__ cursor, int N) {
    __shared__ int sh[1024];
    int t = threadIdx.x;
    int i = blockIdx.x * 1024 + t;
    int c = (i < N) ? cnt[i] : 0;
    sh[t] = c;
    __syncthreads();
    for (int d = 1; d < 1024; d <<= 1) {
        int add = (t >= d) ? sh[t - d] : 0;
        __syncthreads();
        sh[t] += add;
        __syncthreads();
    }
    if (i < N) {
        int incl = bsum[blockIdx.x] + sh[t];
        offsets[i + 1] = incl;
        cursor[i] = incl - c;
    }
    if (i == 0) offsets[0] = 0;
}

// ---------- CSR fill: one WG per bin, cursor slice in LDS ----------
__global__ __launch_bounds__(1024) void k_fill3(const unsigned int* __restrict__ binned,
                                                const int* __restrict__ binCursor,
                                                int* __restrict__ cursor,
                                                int* __restrict__ csr,
                                                int cap, int N) {
    __shared__ int cur[1024];
    int b = blockIdx.x;
    int t = threadIdx.x;
    int g = b * 1024 + t;
    if (g < N) cur[t] = cursor[g];
    __syncthreads();
    int n = min(binCursor[b], cap);
    const unsigned int* p = binned + (size_t)b * cap;
    for (int i = t; i < n; i += 1024) {
        unsigned int w = __builtin_nontemporal_load(p + i);
        int pos = atomicAdd(&cur[w & 1023], 1);
        csr[pos] = (int)(w >> 10);
    }
    __syncthreads();
    if (g < N) cursor[g] = cur[t];   // final positions, for the overflow valve
}

// ---------- drain overflow valve (normally 0 edges) ----------
__global__ void k_ovf(const int* __restrict__ ovfCnt, const v2i* __restrict__ ovf,
                      int* __restrict__ cursor, int* __restrict__ csr) {
    int n = min(*ovfCnt, OVF_CAP);
    for (int i = threadIdx.x; i < n; i += 256) {
        v2i e = ovf[i];
        int pos = atomicAdd(&cursor[e.y], 1);
        csr[pos] = e.x;
    }
}

// ---------- GEMM1: h1' = (x @ W1) * dinv[row], fp16-packed [N,32] __half2 ----------
// Tiled: 64 rows x 64 cols per block, 4x4 register tile per thread, x staged
// TRANSPOSED in LDS (R7 post-mortem: scalar dependent x loads were an 8x
// latency wall - VALUBusy 19%, 84us vs 10us FMA floor).
__global__ __launch_bounds__(256) void k_gemm1t(const float* __restrict__ x,
                                                const float* __restrict__ W,
                                                const float* __restrict__ dinv,
                                                __half2* __restrict__ h1, int N) {
    __shared__ float xsT[DIM_IN * 64];   // [k][row] transposed tile, 32KB
    __shared__ float Ws[DIM_IN * DIM_HID];  // [k][col], 32KB
    int t = threadIdx.x;
    int row0 = blockIdx.x * 64;

    // stage W (coalesced float4)
#pragma unroll
    for (int i = 0; i < 8; i++)
        ((float4*)Ws)[t + 256 * i] = ((const float4*)W)[t + 256 * i];

    // stage x tile transposed: thread reads float4 of a row, scatter-writes 4 ks
#pragma unroll
    for (int i = 0; i < 8; i++) {
        int idx = t * 8 + i;             // 2048 float4 slots = 64 rows x 32 chunks
        int r = idx >> 5;                // local row
        int kc = idx & 31;               // k chunk (4 floats)
        int row = row0 + r;
        float4 v = (row < N) ? ((const float4*)(x + (size_t)row * DIM_IN))[kc]
                             : make_float4(0.f, 0.f, 0.f, 0.f);
        xsT[(4 * kc + 0) * 64 + r] = v.x;
        xsT[(4 * kc + 1) * 64 + r] = v.y;
        xsT[(4 * kc + 2) * 64 + r] = v.z;
        xsT[(4 * kc + 3) * 64 + r] = v.w;
    }
    __syncthreads();

    int c = t & 15;                      // col group: cols 4c..4c+3
    int r = t >> 4;                      // row group: rows 4r..4r+3
    float acc[4][4] = {};

#pragma unroll 4
    for (int k = 0; k < DIM_IN; k++) {
        float4 xa = *(const float4*)&xsT[k * 64 + 4 * r];
        float4 wb = *(const float4*)&Ws[k * DIM_HID + 4 * c];
#pragma unroll
        for (int i = 0; i < 4; i++) {
            float xi = (i == 0) ? xa.x : (i == 1) ? xa.y : (i == 2) ? xa.z : xa.w;
            acc[i][0] = fmaf(xi, wb.x, acc[i][0]);
            acc[i][1] = fmaf(xi, wb.y, acc[i][1]);
            acc[i][2] = fmaf(xi, wb.z, acc[i][2]);
            acc[i][3] = fmaf(xi, wb.w, acc[i][3]);
        }
    }

#pragma unroll
    for (int i = 0; i < 4; i++) {
        int row = row0 + 4 * r + i;
        if (row < N) {
            float d = dinv[row];
            __half2 p0 = __floats2half2_rn(acc[i][0] * d, acc[i][1] * d);
            __half2 p1 = __floats2half2_rn(acc[i][2] * d, acc[i][3] * d);
            h1[(size_t)row * 32 + 2 * c] = p0;
            h1[(size_t)row * 32 + 2 * c + 1] = p1;
        }
    }
}

// ---------- agg1: g = relu(di*(sum h1'[src] + h1'[node]) + b1); h2' = (g@W2)*di ----------
// Half-wave per node: 32 lanes x u32(__half2) = one 128B row per gather.
__global__ __launch_bounds__(256) void k_agg1(const __half2* __restrict__ h1,
                                              const int* __restrict__ csr,
                                              const int* __restrict__ offsets,
                                              const float* __restrict__ dinv,
                                              const float* __restrict__ b1,
                                              const float* __restrict__ W2,
                                              float4* __restrict__ h2, int N) {
    int t = threadIdx.x;
    int hl = t & 31;
    int node = blockIdx.x * 8 + (t >> 5);
    if (node >= N) return;

    float di = dinv[node];
    int beg = offsets[node], end = offsets[node + 1];
    float2 acc = __half22float2(h1[(size_t)node * 32 + hl]);  // self-loop (pre-scaled)

    int e = beg;
    for (; e + 3 < end; e += 4) {
        int s0 = csr[e], s1 = csr[e + 1], s2 = csr[e + 2], s3 = csr[e + 3];
        float2 f0 = __half22float2(h1[(size_t)s0 * 32 + hl]);
        float2 f1 = __half22float2(h1[(size_t)s1 * 32 + hl]);
        float2 f2 = __half22float2(h1[(size_t)s2 * 32 + hl]);
        float2 f3 = __half22float2(h1[(size_t)s3 * 32 + hl]);
        acc.x += (f0.x + f1.x) + (f2.x + f3.x);
        acc.y += (f0.y + f1.y) + (f2.y + f3.y);
    }
    for (; e < end; e++) {
        float2 f = __half22float2(h1[(size_t)csr[e] * 32 + hl]);
        acc.x += f.x;
        acc.y += f.y;
    }

    float2 bb = ((const float2*)b1)[hl];
    float gx = fmaxf(fmaf(acc.x, di, bb.x), 0.f);
    float gy = fmaxf(fmaf(acc.y, di, bb.y), 0.f);

    const float* w0 = W2 + (2 * hl) * 3;
    const float* w1 = W2 + (2 * hl + 1) * 3;
    float v0 = gx * w0[0] + gy * w1[0];
    float v1 = gx * w0[1] + gy * w1[1];
    float v2 = gx * w0[2] + gy * w1[2];
#pragma unroll
    for (int off = 16; off > 0; off >>= 1) {
        v0 += __shfl_xor(v0, off, 64);
        v1 += __shfl_xor(v1, off, 64);
        v2 += __shfl_xor(v2, off, 64);
    }
    if (hl == 0) h2[node] = make_float4(v0 * di, v1 * di, v2 * di, 0.f);
}

// ---------- agg2: out = di*(sum h2'[src] + h2'[node]) + b2 ----------
__global__ __launch_bounds__(256) void k_agg2(const float4* __restrict__ h2,
                                              const int* __restrict__ csr,
                                              const int* __restrict__ offsets,
                                              const float* __restrict__ dinv,
                                              const float* __restrict__ b2,
                                              float* __restrict__ out, int N) {
    int t = threadIdx.x;
    int lane = t & 63;
    int node = blockIdx.x * 4 + (t >> 6);
    if (node >= N) return;

    float di = dinv[node];
    int beg = offsets[node], end = offsets[node + 1];
    float a0 = 0.f, a1 = 0.f, a2 = 0.f;
    for (int e = beg + lane; e < end; e += 64) {
        float4 h = h2[csr[e]];
        a0 += h.x;
        a1 += h.y;
        a2 += h.z;
    }
#pragma unroll
    for (int off = 32; off > 0; off >>= 1) {
        a0 += __shfl_xor(a0, off, 64);
        a1 += __shfl_xor(a1, off, 64);
        a2 += __shfl_xor(a2, off, 64);
    }
    if (lane == 0) {
        float4 hs = h2[node];
        out[(size_t)node * 3 + 0] = fmaf(a0 + hs.x, di, b2[0]);
        out[(size_t)node * 3 + 1] = fmaf(a1 + hs.y, di, b2[1]);
        out[(size_t)node * 3 + 2] = fmaf(a2 + hs.z, di, b2[2]);
    }
}

extern "C" void kernel_launch(void* const* d_in, const int* in_sizes, int n_in,
                              void* d_out, int out_size, void* d_ws, size_t ws_size,
                              hipStream_t stream) {
    const float* x = (const float*)d_in[0];
    const int* eidx = (const int*)d_in[1];
    const float* W1 = (const float*)d_in[2];
    const float* b1 = (const float*)d_in[3];
    const float* W2 = (const float*)d_in[4];
    const float* b2 = (const float*)d_in[5];
    float* out = (float*)d_out;

    const int N = in_sizes[0] / DIM_IN;   // 100000
    const int E = in_sizes[1] / 2;        // 3200000
    const int NB = (N + 1023) >> 10;      // dst bins of 1024 nodes (<=128)

    char* w = (char*)d_ws;
    size_t off = 0;
    auto carve = [&](size_t bytes) -> char* {
        char* p = w + off;
        off += (bytes + 255) & ~(size_t)255;
        return p;
    };
    int* flag = (int*)carve(16);
    int* cnt = (int*)carve((size_t)N * 4);
    int* offsets = (int*)carve((size_t)(N + 1) * 4);
    int* cursor = (int*)carve((size_t)N * 4);
    int* bsum = (int*)carve(1024 * 4);
    float* dinv = (float*)carve((size_t)N * 4);
    int* csr = (int*)carve((size_t)E * 4);
    int* binCursor = (int*)carve(128 * 4);
    int* ovfCnt = (int*)carve(16);
    v2i* ovf = (v2i*)carve((size_t)OVF_CAP * 8);
    float4* h2 = (float4*)carve((size_t)N * 16);

    // uni region: packed binned words (msplit..fill3), then aliased by fp16 h1'.
    size_t h1_bytes = (size_t)N * DIM_HID * 2;
    int capDes = E / NB + E / NB / 16 + 256;     // mean + margin
    size_t binned_des = (size_t)NB * capDes * 4;
    size_t uni_avail = (ws_size > off + 256) ? (ws_size - off - 256) : h1_bytes;
    size_t uni_bytes = binned_des > h1_bytes ? binned_des : h1_bytes;
    if (uni_bytes > uni_avail) uni_bytes = uni_avail > h1_bytes ? uni_avail : h1_bytes;
    char* uni = carve(uni_bytes);
    unsigned int* binned = (unsigned int*)uni;
    __half2* h1 = (__half2*)uni;        // aliased: valid only after k_fill3
    int cap = (int)(uni_bytes / ((size_t)NB * 4));
    if (cap > capDes) cap = capDes;

    (void)hipMemsetAsync(binCursor, 0, 128 * 4 + 256, stream);  // binCursor + ovfCnt
    k_detect<<<1, 64, 0, stream>>>(eidx, flag);

    k_msplit2<<<MS_WGS, 256, 0, stream>>>(eidx, flag, binCursor, binned,
                                          ovfCnt, ovf, E, NB, cap);
    k_binhist<<<NB, 1024, 0, stream>>>(binned, binCursor, cnt, cap, N);

    int NBLK = (N + 1023) / 1024;
    k_s1<<<NBLK, 1024, 0, stream>>>(cnt, dinv, bsum, N);
    k_s2<<<1, 64, 0, stream>>>(bsum, NBLK);
    k_s3<<<NBLK, 1024, 0, stream>>>(cnt, bsum, offsets, cursor, N);

    k_fill3<<<NB, 1024, 0, stream>>>(binned, binCursor, cursor, csr, cap, N);
    k_ovf<<<1, 256, 0, stream>>>(ovfCnt, ovf, cursor, csr);

    k_gemm1t<<<(N + 63) / 64, 256, 0, stream>>>(x, W1, dinv, h1, N);
    k_agg1<<<(N + 7) / 8, 256, 0, stream>>>(h1, csr, offsets, dinv, b1, W2, h2, N);
    k_agg2<<<(N + 3) / 4, 256, 0, stream>>>(h2, csr, offsets, dinv, b2, out, N);
}

// Round 9
// 236.061 us; speedup vs baseline: 3.1227x; 1.1429x over previous
//
#include <hip/hip_runtime.h>
#include <hip/hip_fp16.h>
#include <cstdint>
#include <cstddef>

#define DIM_IN 128
#define DIM_HID 64
#define MS_TILE 2048      // edges per multisplit tile
#define MS_WGS 1024       // msplit workgroups
#define OVF_CAP 32768     // overflow valve capacity (edges)
#define BSH 8             // bin shift: 256-node bins
#define BINSZ 256
#define MAXNB 512
#define CAPL 10240        // LDS-staged edges per bin (40KB); mean 8184, ~20 sigma

// native clang vectors (nontemporal builtins reject HIP_vector_type classes)
typedef int v2i __attribute__((ext_vector_type(2)));

// ---------- edge dtype detection: int32 (stride 1) vs int64 (stride 2) ----------
__global__ void k_detect(const int* __restrict__ e, int* __restrict__ flag) {
    if (blockIdx.x == 0 && threadIdx.x == 0) {
        int o = 0;
        for (int j = 1; j < 128; j += 2) o |= e[j];
        flag[0] = (o == 0) ? 2 : 1;
    }
}

// ---------- multisplit: eidx -> 391 dst-bins of packed (src<<8|ldst) words ----------
__global__ __launch_bounds__(256) void k_msplit2(const int* __restrict__ eidx,
                                                 const int* __restrict__ flag,
                                                 int* __restrict__ binCursor,
                                                 unsigned int* __restrict__ binned,
                                                 int* __restrict__ ovfCnt,
                                                 v2i* __restrict__ ovf,
                                                 int E, int NB, int cap) {
    __shared__ int hist[MAXNB], base[MAXNB], scanb[MAXNB], s4[128];
    __shared__ v2i buf[MS_TILE];  // {packed word, bin}
    int t = threadIdx.x;
    int st = flag[0];
    int ntiles = (E + MS_TILE - 1) / MS_TILE;

    for (int tile = blockIdx.x; tile < ntiles; tile += gridDim.x) {
        int e0 = tile * MS_TILE;
        int cntE = min(MS_TILE, E - e0);

        unsigned int words[8];
        int bins[8];
#pragma unroll
        for (int j = 0; j < 8; j++) {
            int e = e0 + t + 256 * j;
            if (e < E) {
                int s, d;
                if (st == 2) {
                    v2i a = __builtin_nontemporal_load((const v2i*)eidx + e);
                    v2i b = __builtin_nontemporal_load((const v2i*)eidx + E + e);
                    s = a.x; d = b.x;
                } else {
                    s = __builtin_nontemporal_load(&eidx[e]);
                    d = __builtin_nontemporal_load(&eidx[E + e]);
                }
                words[j] = ((unsigned int)s << BSH) | (unsigned int)(d & (BINSZ - 1));
                bins[j] = d >> BSH;
            } else {
                bins[j] = -1;
            }
        }

        hist[t] = 0; hist[t + 256] = 0;
        __syncthreads();
#pragma unroll
        for (int j = 0; j < 8; j++)
            if (bins[j] >= 0) atomicAdd(&hist[bins[j]], 1);
        __syncthreads();
        // 2-level exclusive scan over <=512 bins
        if (t < 128)
            s4[t] = hist[4 * t] + hist[4 * t + 1] + hist[4 * t + 2] + hist[4 * t + 3];
        __syncthreads();
        if (t == 0) {
            int run = 0;
            for (int b = 0; b < 128; b++) { int v = s4[b]; s4[b] = run; run += v; }
        }
        __syncthreads();
        if (t < 128) {
            int r = s4[t];
#pragma unroll
            for (int j = 0; j < 4; j++) { scanb[4 * t + j] = r; r += hist[4 * t + j]; }
        }
        __syncthreads();
        for (int b = t; b < NB; b += 256)
            if (hist[b] > 0) base[b] = atomicAdd(&binCursor[b], hist[b]);
        __syncthreads();
        hist[t] = 0; hist[t + 256] = 0;   // reuse as rank counters
        __syncthreads();
#pragma unroll
        for (int j = 0; j < 8; j++) {
            if (bins[j] >= 0) {
                int r = atomicAdd(&hist[bins[j]], 1);
                buf[scanb[bins[j]] + r] = (v2i){(int)words[j], bins[j]};
            }
        }
        __syncthreads();
        for (int j = t; j < cntE; j += 256) {
            v2i p = buf[j];
            int b = p.y;
            int local = base[b] + (j - scanb[b]);
            if (local < cap) {
                binned[(size_t)b * cap + local] = (unsigned int)p.x;
            } else {
                int o = atomicAdd(ovfCnt, 1);
                if (o < OVF_CAP)
                    ovf[o] = (v2i){(int)((unsigned int)p.x >> BSH),
                                   (b << BSH) | (p.x & (BINSZ - 1))};
            }
        }
        __syncthreads();
    }
}

// ---------- per-bin degree histogram in LDS (no global atomics) ----------
__global__ __launch_bounds__(256) void k_binhist(const unsigned int* __restrict__ binned,
                                                 const int* __restrict__ binCursor,
                                                 int* __restrict__ cnt,
                                                 int cap, int N) {
    __shared__ int hist[BINSZ];
    int b = blockIdx.x;
    int t = threadIdx.x;
    hist[t] = 0;
    __syncthreads();
    int n = min(binCursor[b], cap);
    const unsigned int* p = binned + (size_t)b * cap;
    for (int i = t; i < n; i += 256) {
        unsigned int w = __builtin_nontemporal_load(p + i);
        atomicAdd(&hist[w & (BINSZ - 1)], 1);
    }
    __syncthreads();
    int g = b * BINSZ + t;
    if (g < N) cnt[g] = hist[t];
}

// ---------- scan S1: per-1024-chunk sums; also dinv = rsqrt(cnt+1) ----------
__global__ __launch_bounds__(1024) void k_s1(const int* __restrict__ cnt,
                                             float* __restrict__ dinv,
                                             int* __restrict__ bsum, int N) {
    __shared__ int sh[1024];
    int t = threadIdx.x;
    int i = blockIdx.x * 1024 + t;
    int c = (i < N) ? cnt[i] : 0;
    if (i < N) dinv[i] = rsqrtf((float)(c + 1));
    sh[t] = c;
    __syncthreads();
    for (int d = 512; d > 0; d >>= 1) {
        if (t < d) sh[t] += sh[t + d];
        __syncthreads();
    }
    if (t == 0) bsum[blockIdx.x] = sh[0];
}

__global__ void k_s2(int* __restrict__ bsum, int NB) {
    if (blockIdx.x == 0 && threadIdx.x == 0) {
        int run = 0;
        for (int b = 0; b < NB; b++) { int v = bsum[b]; bsum[b] = run; run += v; }
    }
}

__global__ __launch_bounds__(1024) void k_s3(const int* __restrict__ cnt,
                                             const int* __restrict__ bsum,
                                             int* __restrict__ offsets,
                                             int* __restrict__ cursor, int N) {
    __shared__ int sh[1024];
    int t = threadIdx.x;
    int i = blockIdx.x * 1024 + t;
    int c = (i < N) ? cnt[i] : 0;
    sh[t] = c;
    __syncthreads();
    for (int d = 1; d < 1024; d <<= 1) {
        int add = (t >= d) ? sh[t - d] : 0;
        __syncthreads();
        sh[t] += add;
        __syncthreads();
    }
    if (i < N) {
        int incl = bsum[blockIdx.x] + sh[t];
        offsets[i + 1] = incl;
        cursor[i] = incl - c;
    }
    if (i == 0) offsets[0] = 0;
}

// ---------- CSR fill: LDS-staged payload, coalesced flush ----------
// R8 post-mortem: scattered 4B csr stores = 5x write amp + 14% occupancy.
// Here: scatter into a 40KB LDS stage at slice-relative positions, then flush
// the bin's contiguous csr slice coalesced (write amp 1.0). Tail path (never
// expected: >20 sigma) uses global atomics after cursor write-back.
__global__ __launch_bounds__(256) void k_fillL(const unsigned int* __restrict__ binned,
                                               const int* __restrict__ binCursor,
                                               const int* __restrict__ offsets,
                                               int* __restrict__ cursor,
                                               int* __restrict__ csr,
                                               int cap, int N) {
    __shared__ int curL[BINSZ];
    __shared__ unsigned int stage[CAPL];
    int b = blockIdx.x;
    int t = threadIdx.x;
    int g0 = b << BSH;
    int g = g0 + t;
    int binBase = offsets[g0];
    int sliceEnd = offsets[min(g0 + BINSZ, N)];
    curL[t] = (g < N) ? offsets[g] - binBase : 0;
    __syncthreads();

    int n = min(binCursor[b], cap);
    const unsigned int* p = binned + (size_t)b * cap;
    int nl = min(n, CAPL);
    for (int i = t; i < nl; i += 256) {
        unsigned int w = __builtin_nontemporal_load(p + i);
        int pos = atomicAdd(&curL[w & (BINSZ - 1)], 1);
        stage[pos] = w >> BSH;
    }
    __syncthreads();

    if (g < N) cursor[g] = binBase + curL[t];   // write back (tail + k_ovf)
    int slice = sliceEnd - binBase;
    for (int i = t; i < slice; i += 256)
        csr[binBase + i] = (int)stage[i];       // coalesced flush
    __syncthreads();
    for (int i = CAPL + t; i < n; i += 256) {   // tail (statistically never)
        unsigned int w = p[i];
        int pos = atomicAdd(&cursor[g0 + (int)(w & (BINSZ - 1))], 1);
        csr[pos] = (int)(w >> BSH);
    }
}

// ---------- drain overflow valve (normally 0 edges) ----------
__global__ void k_ovf(const int* __restrict__ ovfCnt, const v2i* __restrict__ ovf,
                      int* __restrict__ cursor, int* __restrict__ csr) {
    int n = min(*ovfCnt, OVF_CAP);
    for (int i = threadIdx.x; i < n; i += 256) {
        v2i e = ovf[i];
        int pos = atomicAdd(&cursor[e.y], 1);
        csr[pos] = e.x;
    }
}

// ---------- GEMM1: h1' = (x @ W1) * dinv[row], fp16-packed [N,32] __half2 ----------
__global__ __launch_bounds__(256) void k_gemm1t(const float* __restrict__ x,
                                                const float* __restrict__ W,
                                                const float* __restrict__ dinv,
                                                __half2* __restrict__ h1, int N) {
    __shared__ float xsT[DIM_IN * 64];      // [k][row] transposed tile, 32KB
    __shared__ float Ws[DIM_IN * DIM_HID];  // [k][col], 32KB
    int t = threadIdx.x;
    int row0 = blockIdx.x * 64;

#pragma unroll
    for (int i = 0; i < 8; i++)
        ((float4*)Ws)[t + 256 * i] = ((const float4*)W)[t + 256 * i];

#pragma unroll
    for (int i = 0; i < 8; i++) {
        int idx = t * 8 + i;
        int r = idx >> 5;
        int kc = idx & 31;
        int row = row0 + r;
        float4 v = (row < N) ? ((const float4*)(x + (size_t)row * DIM_IN))[kc]
                             : make_float4(0.f, 0.f, 0.f, 0.f);
        xsT[(4 * kc + 0) * 64 + r] = v.x;
        xsT[(4 * kc + 1) * 64 + r] = v.y;
        xsT[(4 * kc + 2) * 64 + r] = v.z;
        xsT[(4 * kc + 3) * 64 + r] = v.w;
    }
    __syncthreads();

    int c = t & 15;
    int r = t >> 4;
    float acc[4][4] = {};

#pragma unroll 4
    for (int k = 0; k < DIM_IN; k++) {
        float4 xa = *(const float4*)&xsT[k * 64 + 4 * r];
        float4 wb = *(const float4*)&Ws[k * DIM_HID + 4 * c];
#pragma unroll
        for (int i = 0; i < 4; i++) {
            float xi = (i == 0) ? xa.x : (i == 1) ? xa.y : (i == 2) ? xa.z : xa.w;
            acc[i][0] = fmaf(xi, wb.x, acc[i][0]);
            acc[i][1] = fmaf(xi, wb.y, acc[i][1]);
            acc[i][2] = fmaf(xi, wb.z, acc[i][2]);
            acc[i][3] = fmaf(xi, wb.w, acc[i][3]);
        }
    }

#pragma unroll
    for (int i = 0; i < 4; i++) {
        int row = row0 + 4 * r + i;
        if (row < N) {
            float d = dinv[row];
            h1[(size_t)row * 32 + 2 * c] = __floats2half2_rn(acc[i][0] * d, acc[i][1] * d);
            h1[(size_t)row * 32 + 2 * c + 1] = __floats2half2_rn(acc[i][2] * d, acc[i][3] * d);
        }
    }
}

// ---------- agg1: g = relu(di*(sum h1'[src] + h1'[node]) + b1); h2' = (g@W2)*di ----------
__global__ __launch_bounds__(256) void k_agg1(const __half2* __restrict__ h1,
                                              const int* __restrict__ csr,
                                              const int* __restrict__ offsets,
                                              const float* __restrict__ dinv,
                                              const float* __restrict__ b1,
                                              const float* __restrict__ W2,
                                              float4* __restrict__ h2, int N) {
    int t = threadIdx.x;
    int hl = t & 31;
    int node = blockIdx.x * 8 + (t >> 5);
    if (node >= N) return;

    float di = dinv[node];
    int beg = offsets[node], end = offsets[node + 1];
    float2 acc = __half22float2(h1[(size_t)node * 32 + hl]);  // self-loop (pre-scaled)

    int e = beg;
    for (; e + 3 < end; e += 4) {
        int s0 = csr[e], s1 = csr[e + 1], s2 = csr[e + 2], s3 = csr[e + 3];
        float2 f0 = __half22float2(h1[(size_t)s0 * 32 + hl]);
        float2 f1 = __half22float2(h1[(size_t)s1 * 32 + hl]);
        float2 f2 = __half22float2(h1[(size_t)s2 * 32 + hl]);
        float2 f3 = __half22float2(h1[(size_t)s3 * 32 + hl]);
        acc.x += (f0.x + f1.x) + (f2.x + f3.x);
        acc.y += (f0.y + f1.y) + (f2.y + f3.y);
    }
    for (; e < end; e++) {
        float2 f = __half22float2(h1[(size_t)csr[e] * 32 + hl]);
        acc.x += f.x;
        acc.y += f.y;
    }

    float2 bb = ((const float2*)b1)[hl];
    float gx = fmaxf(fmaf(acc.x, di, bb.x), 0.f);
    float gy = fmaxf(fmaf(acc.y, di, bb.y), 0.f);

    const float* w0 = W2 + (2 * hl) * 3;
    const float* w1 = W2 + (2 * hl + 1) * 3;
    float v0 = gx * w0[0] + gy * w1[0];
    float v1 = gx * w0[1] + gy * w1[1];
    float v2 = gx * w0[2] + gy * w1[2];
#pragma unroll
    for (int off = 16; off > 0; off >>= 1) {
        v0 += __shfl_xor(v0, off, 64);
        v1 += __shfl_xor(v1, off, 64);
        v2 += __shfl_xor(v2, off, 64);
    }
    if (hl == 0) h2[node] = make_float4(v0 * di, v1 * di, v2 * di, 0.f);
}

// ---------- agg2: out = di*(sum h2'[src] + h2'[node]) + b2 ----------
__global__ __launch_bounds__(256) void k_agg2(const float4* __restrict__ h2,
                                              const int* __restrict__ csr,
                                              const int* __restrict__ offsets,
                                              const float* __restrict__ dinv,
                                              const float* __restrict__ b2,
                                              float* __restrict__ out, int N) {
    int t = threadIdx.x;
    int lane = t & 63;
    int node = blockIdx.x * 4 + (t >> 6);
    if (node >= N) return;

    float di = dinv[node];
    int beg = offsets[node], end = offsets[node + 1];
    float a0 = 0.f, a1 = 0.f, a2 = 0.f;
    for (int e = beg + lane; e < end; e += 64) {
        float4 h = h2[csr[e]];
        a0 += h.x;
        a1 += h.y;
        a2 += h.z;
    }
#pragma unroll
    for (int off = 32; off > 0; off >>= 1) {
        a0 += __shfl_xor(a0, off, 64);
        a1 += __shfl_xor(a1, off, 64);
        a2 += __shfl_xor(a2, off, 64);
    }
    if (lane == 0) {
        float4 hs = h2[node];
        out[(size_t)node * 3 + 0] = fmaf(a0 + hs.x, di, b2[0]);
        out[(size_t)node * 3 + 1] = fmaf(a1 + hs.y, di, b2[1]);
        out[(size_t)node * 3 + 2] = fmaf(a2 + hs.z, di, b2[2]);
    }
}

extern "C" void kernel_launch(void* const* d_in, const int* in_sizes, int n_in,
                              void* d_out, int out_size, void* d_ws, size_t ws_size,
                              hipStream_t stream) {
    const float* x = (const float*)d_in[0];
    const int* eidx = (const int*)d_in[1];
    const float* W1 = (const float*)d_in[2];
    const float* b1 = (const float*)d_in[3];
    const float* W2 = (const float*)d_in[4];
    const float* b2 = (const float*)d_in[5];
    float* out = (float*)d_out;

    const int N = in_sizes[0] / DIM_IN;   // 100000
    const int E = in_sizes[1] / 2;        // 3200000
    const int NB = (N + BINSZ - 1) >> BSH;  // 391 bins of 256 nodes

    char* w = (char*)d_ws;
    size_t off = 0;
    auto carve = [&](size_t bytes) -> char* {
        char* p = w + off;
        off += (bytes + 255) & ~(size_t)255;
        return p;
    };
    int* flag = (int*)carve(16);
    int* cnt = (int*)carve((size_t)N * 4);
    int* offsets = (int*)carve((size_t)(N + 1) * 4);
    int* cursor = (int*)carve((size_t)N * 4);
    int* bsum = (int*)carve(1024 * 4);
    float* dinv = (float*)carve((size_t)N * 4);
    int* csr = (int*)carve((size_t)E * 4);
    int* binCursor = (int*)carve(MAXNB * 4);
    int* ovfCnt = (int*)carve(16);
    v2i* ovf = (v2i*)carve((size_t)OVF_CAP * 8);
    float4* h2 = (float4*)carve((size_t)N * 16);

    // uni region: packed binned words (msplit..fillL), then aliased by fp16 h1'.
    size_t h1_bytes = (size_t)N * DIM_HID * 2;
    int capDes = E / NB + E / NB / 16 + 128;     // mean + margin
    size_t binned_des = (size_t)NB * capDes * 4;
    size_t uni_avail = (ws_size > off + 256) ? (ws_size - off - 256) : h1_bytes;
    size_t uni_bytes = binned_des > h1_bytes ? binned_des : h1_bytes;
    if (uni_bytes > uni_avail) uni_bytes = uni_avail > h1_bytes ? uni_avail : h1_bytes;
    char* uni = carve(uni_bytes);
    unsigned int* binned = (unsigned int*)uni;
    __half2* h1 = (__half2*)uni;        // aliased: valid only after k_fillL
    int cap = (int)(uni_bytes / ((size_t)NB * 4));
    if (cap > capDes) cap = capDes;

    (void)hipMemsetAsync(binCursor, 0, MAXNB * 4 + 256, stream);  // binCursor + ovfCnt
    k_detect<<<1, 64, 0, stream>>>(eidx, flag);

    k_msplit2<<<MS_WGS, 256, 0, stream>>>(eidx, flag, binCursor, binned,
                                          ovfCnt, ovf, E, NB, cap);
    k_binhist<<<NB, 256, 0, stream>>>(binned, binCursor, cnt, cap, N);

    int NBLK = (N + 1023) / 1024;
    k_s1<<<NBLK, 1024, 0, stream>>>(cnt, dinv, bsum, N);
    k_s2<<<1, 64, 0, stream>>>(bsum, NBLK);
    k_s3<<<NBLK, 1024, 0, stream>>>(cnt, bsum, offsets, cursor, N);

    k_fillL<<<NB, 256, 0, stream>>>(binned, binCursor, offsets, cursor, csr, cap, N);
    k_ovf<<<1, 256, 0, stream>>>(ovfCnt, ovf, cursor, csr);

    k_gemm1t<<<(N + 63) / 64, 256, 0, stream>>>(x, W1, dinv, h1, N);
    k_agg1<<<(N + 7) / 8, 256, 0, stream>>>(h1, csr, offsets, dinv, b1, W2, h2, N);
    k_agg2<<<(N + 3) / 4, 256, 0, stream>>>(h2, csr, offsets, dinv, b2, out, N);
}